// Round 1
// baseline (897.895 us; speedup 1.0000x reference)
//
#include <hip/hip_runtime.h>

#define LAT   128
#define NSUB  64
#define NLEAF 2048
#define NNODES 50000
#define OPROW 2047   // 2^11 - 1

__device__ __forceinline__ float sigm(float x)   { return 1.f / (1.f + __expf(-x)); }
__device__ __forceinline__ float tanh_f(float x) { float e = __expf(2.f * x); return 1.f - 2.f / (e + 1.f); }

// ---------------------------------------------------------------------------
// Build W_pair[256][512]: rows 0-127 = lh weights, rows 128-255 = rh weights.
// Gate g (col/128): 0=i, 1=lf, 2=rf, 3=u.
// lh side uses W_child[2g], rh side uses W_child[2g+1].
__global__ __launch_bounds__(256) void k_prep_wpair(const float* __restrict__ Wc,
                                                    float* __restrict__ Wp) {
    int i = blockIdx.x * 256 + threadIdx.x;      // 0 .. 131071
    int l = i >> 9, c = i & 511;
    int g = c >> 7, d = c & 127;
    float v;
    if (l < 128) v = Wc[(2 * g) * 16384 + l * 128 + d];
    else         v = Wc[(2 * g + 1) * 16384 + (l - 128) * 128 + d];
    Wp[i] = v;
}

// op_table[32][512]: char_emb[t] @ W_x[gx(g)] + b_x[gx(g)] + b_child[2g] + b_child[2g+1]
__global__ __launch_bounds__(256) void k_prep_table(const float* __restrict__ ce,
                                                    const float* __restrict__ Wx,
                                                    const float* __restrict__ bx,
                                                    const float* __restrict__ bc,
                                                    float* __restrict__ tab) {
    int i = blockIdx.x * 256 + threadIdx.x;      // 0 .. 16383
    int t = i >> 9, c = i & 511;
    int g = c >> 7, d = c & 127;
    int gx = (g == 0) ? 0 : ((g == 3) ? 2 : 1);
    float acc = bx[gx * 128 + d] + bc[(2 * g) * 128 + d] + bc[(2 * g + 1) * 128 + d];
    const float* x = ce + t * 128;
    const float* w = Wx + gx * 16384 + d;
    for (int l = 0; l < 128; ++l) acc += x[l] * w[l * 128];
    tab[i] = acc;
}

// c_tab/h_tab for all 50000 nodes: 16 nodes per block.
__global__ __launch_bounds__(256) void k_prep_nodes(const float* __restrict__ ne,
                                                    const float* __restrict__ Wl,
                                                    const float* __restrict__ bl,
                                                    float* __restrict__ c_tab,
                                                    float* __restrict__ h_tab) {
    __shared__ float X[16][128];
    const int t = threadIdx.x;
    const int nb = blockIdx.x * 16;
    {
        int n = t >> 4, l0 = (t & 15) * 8;
        const float* src = ne + (nb + n) * LAT + l0;
        *(float4*)&X[n][l0]     = *(const float4*)(src);
        *(float4*)&X[n][l0 + 4] = *(const float4*)(src + 4);
    }
    __syncthreads();
    const int d0 = (t & 31) * 4;
    const int n0 = (t >> 5) * 2;
    float ac[2][4] = {}, ah[2][4] = {};
    for (int l = 0; l < LAT; ++l) {
        float w0[4], w1[4];
        *(float4*)w0 = *(const float4*)(Wl + l * LAT + d0);           // W_leaf[0]
        *(float4*)w1 = *(const float4*)(Wl + 16384 + l * LAT + d0);   // W_leaf[1]
        float x0 = X[n0][l], x1 = X[n0 + 1][l];
#pragma unroll
        for (int i = 0; i < 4; ++i) {
            ac[0][i] += x0 * w0[i]; ac[1][i] += x1 * w0[i];
            ah[0][i] += x0 * w1[i]; ah[1][i] += x1 * w1[i];
        }
    }
#pragma unroll
    for (int n = 0; n < 2; ++n)
#pragma unroll
        for (int i = 0; i < 4; ++i) {
            float cc = ac[n][i] + bl[d0 + i];
            float hp = ah[n][i] + bl[LAT + d0 + i];
            c_tab[(nb + n0 + n) * LAT + d0 + i] = cc;
            h_tab[(nb + n0 + n) * LAT + d0 + i] = sigm(hp) * tanh_f(cc);
        }
}

// ---------------------------------------------------------------------------
// One tree level: 16 pairs per block. v = [lh|rh] @ W_pair, gates fused.
__global__ __launch_bounds__(256) void k_level(const float* __restrict__ c_src,
                                               const float* __restrict__ h_src,
                                               const int* __restrict__ gather,
                                               float* __restrict__ c_out,
                                               float* __restrict__ h_out,
                                               const float* __restrict__ Wp,
                                               const float* __restrict__ tab,
                                               const int* __restrict__ op_idx,
                                               int op_start, int mshift) {
    __shared__ float lhs[16][257];   // [pair][k-dim 0..255]
    __shared__ float wt[16 * 512];   // W k-tile; reused as v-buffer
    const int t = threadIdx.x;
    const int m = 1 << mshift;
    const int pbase = blockIdx.x * 16;

    // stage lhs: thread -> (pair, 16-float segment)
    {
        const int pl = t >> 4, seg = t & 15;
        const int pgl = pbase + pl;
        const int ks = pgl >> mshift;
        const int j = pgl & (m - 1);
        int child = (ks << (mshift + 1)) + 2 * j + (seg >> 3);
        int row = gather ? gather[child] : child;
        const float* hp = h_src + row * LAT + (seg & 7) * 16;
        float4 a0 = *(const float4*)(hp + 0);
        float4 a1 = *(const float4*)(hp + 4);
        float4 a2 = *(const float4*)(hp + 8);
        float4 a3 = *(const float4*)(hp + 12);
        float* dst = &lhs[pl][seg * 16];
        dst[0] = a0.x; dst[1] = a0.y; dst[2]  = a0.z; dst[3]  = a0.w;
        dst[4] = a1.x; dst[5] = a1.y; dst[6]  = a1.z; dst[7]  = a1.w;
        dst[8] = a2.x; dst[9] = a2.y; dst[10] = a2.z; dst[11] = a2.w;
        dst[12] = a3.x; dst[13] = a3.y; dst[14] = a3.z; dst[15] = a3.w;
    }

    float acc[4][8];
#pragma unroll
    for (int j = 0; j < 4; ++j)
#pragma unroll
        for (int i = 0; i < 8; ++i) acc[j][i] = 0.f;

    const int c8 = (t & 63) * 8;       // 8 output cols
    const int pg = (t >> 6) * 4;       // 4 pairs

    for (int kt = 0; kt < 16; ++kt) {
        __syncthreads();
#pragma unroll
        for (int i = 0; i < 8; ++i) {
            int f = t + 256 * i;               // float4 id
            int row = f >> 7;                  // 0..15
            int c4 = (f & 127) << 2;           // 0..508
            *(float4*)&wt[row * 512 + c4] = *(const float4*)(Wp + (kt * 16 + row) * 512 + c4);
        }
        __syncthreads();
        const int kb = kt * 16;
#pragma unroll
        for (int k = 0; k < 16; ++k) {
            float w0[4], w1[4];
            *(float4*)w0 = *(const float4*)&wt[k * 512 + c8];
            *(float4*)w1 = *(const float4*)&wt[k * 512 + c8 + 4];
#pragma unroll
            for (int j = 0; j < 4; ++j) {
                float lv = lhs[pg + j][kb + k];
#pragma unroll
                for (int i = 0; i < 4; ++i) {
                    acc[j][i]     += lv * w0[i];
                    acc[j][4 + i] += lv * w1[i];
                }
            }
        }
    }
    __syncthreads();
    // scatter v into LDS (reuse wt) so the epilogue can see all 4 gates per (p,d)
#pragma unroll
    for (int j = 0; j < 4; ++j)
#pragma unroll
        for (int i = 0; i < 8; ++i) wt[(pg + j) * 512 + c8 + i] = acc[j][i];
    __syncthreads();

    {
        const int p = t >> 4;
        const int d0 = (t & 15) * 8;
        const int pgl = pbase + p;
        const int ks = pgl >> mshift;
        const int j = pgl & (m - 1);
        const int op = op_idx[ks * OPROW + op_start + j];
        const float* tb = tab + op * 512;
        int left = (ks << (mshift + 1)) + 2 * j;
        int rl = gather ? gather[left] : left;
        int rr = gather ? gather[left + 1] : left + 1;
        const float* lcp = c_src + rl * LAT + d0;
        const float* rcp = c_src + rr * LAT + d0;
        float* co = c_out + pgl * LAT + d0;
        float* ho = h_out + pgl * LAT + d0;
#pragma unroll
        for (int i = 0; i < 8; ++i) {
            float vi = wt[p * 512 + 0   + d0 + i] + tb[0   + d0 + i];
            float vl = wt[p * 512 + 128 + d0 + i] + tb[128 + d0 + i];
            float vr = wt[p * 512 + 256 + d0 + i] + tb[256 + d0 + i];
            float vu = wt[p * 512 + 384 + d0 + i] + tb[384 + d0 + i];
            float ig = sigm(vi), lf = sigm(vl), rf = sigm(vr), u = tanh_f(vu);
            float cc = ig * u + lf * lcp[i] + rf * rcp[i];
            co[i] = cc;
            ho[i] = tanh_f(cc);
        }
    }
}

// ---------------------------------------------------------------------------
__global__ __launch_bounds__(128) void k_and(const float* __restrict__ c_root,
                                             const float* __restrict__ h_root,
                                             const float* __restrict__ Wa,
                                             const float* __restrict__ ba,
                                             float* __restrict__ c2,
                                             float* __restrict__ h2) {
    __shared__ float cs[128], hs[128];
    const int k = blockIdx.x, d = threadIdx.x;
    cs[d] = c_root[k * 128 + d];
    hs[d] = h_root[k * 128 + d];
    __syncthreads();
    float a = ba[d], b = ba[128 + d];
    for (int l = 0; l < 128; ++l) {
        a += cs[l] * Wa[l * 128 + d];
        b += hs[l] * Wa[16384 + l * 128 + d];
    }
    c2[k * 128 + d] = a;
    h2[k * 128 + d] = b;
}

__global__ __launch_bounds__(128) void k_final(const float* __restrict__ c2,
                                               const float* __restrict__ h2,
                                               const float* __restrict__ init_e,
                                               const float* __restrict__ Wo,
                                               const float* __restrict__ bo,
                                               float* __restrict__ out) {
    __shared__ float s[384];
    const int d = threadIdx.x;
    float cm = c2[d], hm = h2[d];
    for (int k = 1; k < 64; ++k) {
        cm = fminf(cm, c2[k * 128 + d]);
        hm = fminf(hm, h2[k * 128 + d]);
    }
    s[d] = init_e[d];
    s[128 + d] = cm;
    s[256 + d] = hm;
    __syncthreads();
    float a = bo[d];
    for (int l = 0; l < 384; ++l) a += s[l] * Wo[l * 128 + d];
    out[d] = tanhf(a);
}

// ---------------------------------------------------------------------------
extern "C" void kernel_launch(void* const* d_in, const int* in_sizes, int n_in,
                              void* d_out, int out_size, void* d_ws, size_t ws_size,
                              hipStream_t stream) {
    const float* node_emb = (const float*)d_in[0];
    const float* init_emb = (const float*)d_in[1];
    const float* char_emb = (const float*)d_in[2];
    const float* W_child  = (const float*)d_in[3];
    const float* b_child  = (const float*)d_in[4];
    const float* W_x      = (const float*)d_in[5];
    const float* b_x      = (const float*)d_in[6];
    const float* W_leaf   = (const float*)d_in[7];
    const float* b_leaf   = (const float*)d_in[8];
    const float* W_and    = (const float*)d_in[9];
    const float* b_and    = (const float*)d_in[10];
    const float* W_oend   = (const float*)d_in[11];
    const float* b_oend   = (const float*)d_in[12];
    const int* leaf_idx   = (const int*)d_in[13];
    const int* op_idx     = (const int*)d_in[14];
    float* out = (float*)d_out;

    float* ws = (float*)d_ws;
    float* Wp    = ws;                       // 131072
    float* tab   = Wp + 131072;              // 16384
    float* c_tab = tab + 16384;              // 6,400,000
    float* h_tab = c_tab + 6400000;          // 6,400,000
    float* Ac    = h_tab + 6400000;          // 8,388,608 (64*1024*128)
    float* Ah    = Ac + 8388608;
    float* Bc    = Ah + 8388608;             // 4,194,304 (64*512*128)
    float* Bh    = Bc + 4194304;
    float* c2    = Bh + 4194304;             // 8192
    float* h2    = c2 + 8192;                // 8192
    (void)ws_size; (void)in_sizes; (void)n_in; (void)out_size;

    k_prep_wpair<<<512, 256, 0, stream>>>(W_child, Wp);
    k_prep_table<<<64, 256, 0, stream>>>(char_emb, W_x, b_x, b_child, tab);
    k_prep_nodes<<<3125, 256, 0, stream>>>(node_emb, W_leaf, b_leaf, c_tab, h_tab);

    for (int d = 0; d < 11; ++d) {
        int m = 1024 >> d;
        int mshift = 10 - d;
        int P = 64 * m;
        int start = 2048 - (2048 >> d);
        const int* gth = nullptr;
        const float *ic, *ih;
        float *oc, *oh;
        if (d == 0)      { ic = c_tab; ih = h_tab; gth = leaf_idx; }
        else if (d & 1)  { ic = Ac; ih = Ah; }
        else             { ic = Bc; ih = Bh; }
        if (d & 1) { oc = Bc; oh = Bh; }
        else       { oc = Ac; oh = Ah; }
        k_level<<<P / 16, 256, 0, stream>>>(ic, ih, gth, oc, oh, Wp, tab, op_idx, start, mshift);
    }

    k_and<<<64, 128, 0, stream>>>(Ac, Ah, W_and, b_and, c2, h2);
    k_final<<<1, 128, 0, stream>>>(c2, h2, init_emb, W_oend, b_oend, out);
}

// Round 2
// 399.207 us; speedup vs baseline: 2.2492x; 2.2492x over previous
//
#include <hip/hip_runtime.h>

#define LAT    128
#define OPROW  2047
#define NNODES 50000

typedef __bf16 bf16x8 __attribute__((ext_vector_type(8)));
typedef float  f32x4  __attribute__((ext_vector_type(4)));

__device__ __forceinline__ float sigm(float x)   { return 1.f / (1.f + __expf(-x)); }
__device__ __forceinline__ float tanh_f(float x) { float e = __expf(2.f * x); return 1.f - 2.f / (e + 1.f); }

// ---------------------------------------------------------------------------
// node_emb fp32 -> bf16
__global__ __launch_bounds__(256) void k_cvt_ne(const float* __restrict__ src,
                                                __bf16* __restrict__ dst) {
    int i = (blockIdx.x * 256 + threadIdx.x) * 8;
    float4 a = *(const float4*)(src + i);
    float4 b = *(const float4*)(src + i + 4);
    bf16x8 v;
    v[0] = (__bf16)a.x; v[1] = (__bf16)a.y; v[2] = (__bf16)a.z; v[3] = (__bf16)a.w;
    v[4] = (__bf16)b.x; v[5] = (__bf16)b.y; v[6] = (__bf16)b.z; v[7] = (__bf16)b.w;
    *(bf16x8*)(dst + i) = v;
}

// WpT[512 cols][256 k] bf16: col c -> gate g=c>>7, d=c&127.
// k<128: W_child[2g][k][d] (lh side); k>=128: W_child[2g+1][k-128][d] (rh side)
__global__ __launch_bounds__(256) void k_prep_wpT(const float* __restrict__ Wc,
                                                  __bf16* __restrict__ WpT) {
    int i = blockIdx.x * 256 + threadIdx.x;     // 0..131071
    int c = i >> 8, k = i & 255;
    int g = c >> 7, d = c & 127;
    float v = (k < 128) ? Wc[(2 * g) * 16384 + k * 128 + d]
                        : Wc[(2 * g + 1) * 16384 + (k - 128) * 128 + d];
    WpT[i] = (__bf16)v;
}

// WlT[256 cols][128 k] bf16: col<128 -> W_leaf[0][k][col] (c), else W_leaf[1][k][col-128] (h-gate)
__global__ __launch_bounds__(256) void k_prep_wlT(const float* __restrict__ Wl,
                                                  __bf16* __restrict__ WlT) {
    int i = blockIdx.x * 256 + threadIdx.x;     // 0..32767
    int c = i >> 7, k = i & 127;
    float v = Wl[(c >> 7) * 16384 + k * 128 + (c & 127)];
    WlT[i] = (__bf16)v;
}

// op_table[32][512] fp32: char_emb[t] @ W_x[gx(g)] + b_x[gx] + b_child[2g] + b_child[2g+1]
__global__ __launch_bounds__(256) void k_prep_table(const float* __restrict__ ce,
                                                    const float* __restrict__ Wx,
                                                    const float* __restrict__ bx,
                                                    const float* __restrict__ bc,
                                                    float* __restrict__ tab) {
    int i = blockIdx.x * 256 + threadIdx.x;     // 0..16383
    int t = i >> 9, c = i & 511;
    int g = c >> 7, d = c & 127;
    int gx = (g == 0) ? 0 : ((g == 3) ? 2 : 1);
    float acc = bx[gx * 128 + d] + bc[(2 * g) * 128 + d] + bc[(2 * g + 1) * 128 + d];
    const float* x = ce + t * 128;
    const float* w = Wx + gx * 16384 + d;
    for (int l = 0; l < 128; ++l) acc += x[l] * w[l * 128];
    tab[i] = acc;
}

// ---------------------------------------------------------------------------
// Leaf tables via MFMA: [50000 x 128] @ WlT^T -> c_tab fp32, h_tab bf16
__global__ __launch_bounds__(256) void k_prep_nodes(const __bf16* __restrict__ ne,
                                                    const __bf16* __restrict__ WlT,
                                                    const float* __restrict__ bl,
                                                    float* __restrict__ c_tab,
                                                    __bf16* __restrict__ h_tab) {
    const int t = threadIdx.x;
    const int w = t >> 6, l = t & 63;
    const int lr = l & 15, lq = l >> 4;
    const int nb = blockIdx.x * 32;
    const int koff = lq * 8;

    int arow[2];
#pragma unroll
    for (int rt = 0; rt < 2; ++rt) {
        int r = nb + rt * 16 + lr;
        arow[rt] = (r < NNODES) ? r : (NNODES - 1);
    }

    f32x4 acc[2][2][2];
#pragma unroll
    for (int rt = 0; rt < 2; ++rt)
#pragma unroll
        for (int g = 0; g < 2; ++g)
#pragma unroll
            for (int ti = 0; ti < 2; ++ti) acc[rt][g][ti] = (f32x4)0.f;

#pragma unroll
    for (int kk = 0; kk < 4; ++kk) {
        bf16x8 af[2];
#pragma unroll
        for (int rt = 0; rt < 2; ++rt)
            af[rt] = *(const bf16x8*)(ne + arow[rt] * 128 + kk * 32 + koff);
#pragma unroll
        for (int g = 0; g < 2; ++g)
#pragma unroll
            for (int ti = 0; ti < 2; ++ti) {
                int col = g * 128 + w * 32 + ti * 16 + lr;
                bf16x8 bb = *(const bf16x8*)(WlT + col * 128 + kk * 32 + koff);
#pragma unroll
                for (int rt = 0; rt < 2; ++rt)
                    acc[rt][g][ti] = __builtin_amdgcn_mfma_f32_16x16x32_bf16(af[rt], bb, acc[rt][g][ti], 0, 0, 0);
            }
    }

#pragma unroll
    for (int rt = 0; rt < 2; ++rt)
#pragma unroll
        for (int j = 0; j < 4; ++j) {
            int r = nb + rt * 16 + lq * 4 + j;
            if (r < NNODES) {
#pragma unroll
                for (int ti = 0; ti < 2; ++ti) {
                    int d = w * 32 + ti * 16 + lr;
                    float cc = acc[rt][0][ti][j] + bl[d];
                    float hp = acc[rt][1][ti][j] + bl[128 + d];
                    c_tab[r * 128 + d] = cc;
                    h_tab[r * 128 + d] = (__bf16)(sigm(hp) * tanh_f(cc));
                }
            }
        }
}

// ---------------------------------------------------------------------------
// One tree level, 32 pairs/block, MFMA, zero LDS.
__global__ __launch_bounds__(256) void k_level(const float* __restrict__ c_src,
                                               const __bf16* __restrict__ h_src,
                                               const int* __restrict__ gather,
                                               float* __restrict__ c_out,
                                               __bf16* __restrict__ h_out,
                                               const __bf16* __restrict__ WpT,
                                               const float* __restrict__ tab,
                                               const int* __restrict__ op_idx,
                                               int op_start, int mshift) {
    const int t = threadIdx.x;
    const int w = t >> 6, l = t & 63;
    const int lr = l & 15, lq = l >> 4;
    const int pbase = blockIdx.x * 32;
    const int koff = lq * 8;

    // child rows for A-fragment loads (A row = lane&15 within row-tile)
    int rowL[2], rowR[2];
#pragma unroll
    for (int rt = 0; rt < 2; ++rt) {
        int p = pbase + rt * 16 + lr;
        int ks = p >> mshift;
        int jj = p & ((1 << mshift) - 1);
        int base = (ks << (mshift + 1)) + 2 * jj;
        rowL[rt] = gather ? gather[base] : base;
        rowR[rt] = gather ? gather[base + 1] : base + 1;
    }

    f32x4 acc[2][4][2];
#pragma unroll
    for (int rt = 0; rt < 2; ++rt)
#pragma unroll
        for (int g = 0; g < 4; ++g)
#pragma unroll
            for (int ti = 0; ti < 2; ++ti) acc[rt][g][ti] = (f32x4)0.f;

#pragma unroll
    for (int kk = 0; kk < 8; ++kk) {
        bf16x8 af[2];
        int ko = (kk & 3) * 32 + koff;
#pragma unroll
        for (int rt = 0; rt < 2; ++rt) {
            int row = (kk < 4) ? rowL[rt] : rowR[rt];
            af[rt] = *(const bf16x8*)(h_src + row * 128 + ko);
        }
        int kw = kk * 32 + koff;
#pragma unroll
        for (int g = 0; g < 4; ++g)
#pragma unroll
            for (int ti = 0; ti < 2; ++ti) {
                int col = g * 128 + w * 32 + ti * 16 + lr;
                bf16x8 bb = *(const bf16x8*)(WpT + col * 256 + kw);
#pragma unroll
                for (int rt = 0; rt < 2; ++rt)
                    acc[rt][g][ti] = __builtin_amdgcn_mfma_f32_16x16x32_bf16(af[rt], bb, acc[rt][g][ti], 0, 0, 0);
            }
    }

    // epilogue: gates + recurrence, fully wave-local
#pragma unroll
    for (int rt = 0; rt < 2; ++rt)
#pragma unroll
        for (int j = 0; j < 4; ++j) {
            int p = pbase + rt * 16 + lq * 4 + j;
            int ks = p >> mshift;
            int jj = p & ((1 << mshift) - 1);
            int op = op_idx[ks * OPROW + op_start + jj];
            int base = (ks << (mshift + 1)) + 2 * jj;
            int rl = gather ? gather[base] : base;
            int rr = gather ? gather[base + 1] : base + 1;
            const float* tb = tab + op * 512;
#pragma unroll
            for (int ti = 0; ti < 2; ++ti) {
                int d = w * 32 + ti * 16 + lr;
                float vi = acc[rt][0][ti][j] + tb[d];
                float vl = acc[rt][1][ti][j] + tb[128 + d];
                float vr = acc[rt][2][ti][j] + tb[256 + d];
                float vu = acc[rt][3][ti][j] + tb[384 + d];
                float lc = c_src[rl * 128 + d];
                float rc = c_src[rr * 128 + d];
                float cc = sigm(vi) * tanh_f(vu) + sigm(vl) * lc + sigm(vr) * rc;
                c_out[p * 128 + d] = cc;
                h_out[p * 128 + d] = (__bf16)tanh_f(cc);
            }
        }
}

// ---------------------------------------------------------------------------
__global__ __launch_bounds__(128) void k_and(const float* __restrict__ c_root,
                                             const __bf16* __restrict__ h_root,
                                             const float* __restrict__ Wa,
                                             const float* __restrict__ ba,
                                             float* __restrict__ c2,
                                             float* __restrict__ h2) {
    __shared__ float cs[128], hs[128];
    const int k = blockIdx.x, d = threadIdx.x;
    cs[d] = c_root[k * 128 + d];
    hs[d] = (float)h_root[k * 128 + d];
    __syncthreads();
    float a = ba[d], b = ba[128 + d];
    for (int l = 0; l < 128; ++l) {
        a += cs[l] * Wa[l * 128 + d];
        b += hs[l] * Wa[16384 + l * 128 + d];
    }
    c2[k * 128 + d] = a;
    h2[k * 128 + d] = b;
}

__global__ __launch_bounds__(128) void k_final(const float* __restrict__ c2,
                                               const float* __restrict__ h2,
                                               const float* __restrict__ init_e,
                                               const float* __restrict__ Wo,
                                               const float* __restrict__ bo,
                                               float* __restrict__ out) {
    __shared__ float s[384];
    const int d = threadIdx.x;
    float cm = c2[d], hm = h2[d];
    for (int k = 1; k < 64; ++k) {
        cm = fminf(cm, c2[k * 128 + d]);
        hm = fminf(hm, h2[k * 128 + d]);
    }
    s[d] = init_e[d];
    s[128 + d] = cm;
    s[256 + d] = hm;
    __syncthreads();
    float a = bo[d];
    for (int l = 0; l < 384; ++l) a += s[l] * Wo[l * 128 + d];
    out[d] = tanhf(a);
}

// ---------------------------------------------------------------------------
extern "C" void kernel_launch(void* const* d_in, const int* in_sizes, int n_in,
                              void* d_out, int out_size, void* d_ws, size_t ws_size,
                              hipStream_t stream) {
    const float* node_emb = (const float*)d_in[0];
    const float* init_emb = (const float*)d_in[1];
    const float* char_emb = (const float*)d_in[2];
    const float* W_child  = (const float*)d_in[3];
    const float* b_child  = (const float*)d_in[4];
    const float* W_x      = (const float*)d_in[5];
    const float* b_x      = (const float*)d_in[6];
    const float* W_leaf   = (const float*)d_in[7];
    const float* b_leaf   = (const float*)d_in[8];
    const float* W_and    = (const float*)d_in[9];
    const float* b_and    = (const float*)d_in[10];
    const float* W_oend   = (const float*)d_in[11];
    const float* b_oend   = (const float*)d_in[12];
    const int* leaf_idx   = (const int*)d_in[13];
    const int* op_idx     = (const int*)d_in[14];
    float* out = (float*)d_out;
    (void)in_sizes; (void)n_in; (void)out_size; (void)ws_size;

    char* p = (char*)d_ws;
    auto carve = [&](size_t bytes) { char* r = p; p += (bytes + 255) & ~255ull; return r; };
    __bf16* WpT   = (__bf16*)carve(512 * 256 * 2);
    __bf16* WlT   = (__bf16*)carve(256 * 128 * 2);
    float*  tab   = (float*)carve(32 * 512 * 4);
    __bf16* ne_bf = (__bf16*)carve((size_t)NNODES * 128 * 2);
    float*  c_tab = (float*)carve((size_t)NNODES * 128 * 4);
    __bf16* h_tab = (__bf16*)carve((size_t)NNODES * 128 * 2);
    float*  Ac    = (float*)carve((size_t)65536 * 128 * 4);
    __bf16* Ah    = (__bf16*)carve((size_t)65536 * 128 * 2);
    float*  Bc    = (float*)carve((size_t)32768 * 128 * 4);
    __bf16* Bh    = (__bf16*)carve((size_t)32768 * 128 * 2);
    float*  c2    = (float*)carve(64 * 128 * 4);
    float*  h2    = (float*)carve(64 * 128 * 4);

    k_cvt_ne    <<<3125, 256, 0, stream>>>(node_emb, ne_bf);
    k_prep_wpT  <<<512, 256, 0, stream>>>(W_child, WpT);
    k_prep_wlT  <<<128, 256, 0, stream>>>(W_leaf, WlT);
    k_prep_table<<<64, 256, 0, stream>>>(char_emb, W_x, b_x, b_child, tab);
    k_prep_nodes<<<(NNODES + 31) / 32, 256, 0, stream>>>(ne_bf, WlT, b_leaf, c_tab, h_tab);

    for (int d = 0; d < 11; ++d) {
        int mshift = 10 - d;
        int P = 65536 >> d;
        int start = 2048 - (2048 >> d);
        const int* gth = nullptr;
        const float* ic; const __bf16* ih;
        float* oc; __bf16* oh;
        if (d == 0)      { ic = c_tab; ih = h_tab; gth = leaf_idx; }
        else if (d & 1)  { ic = Ac; ih = Ah; }
        else             { ic = Bc; ih = Bh; }
        if (d & 1) { oc = Bc; oh = Bh; }
        else       { oc = Ac; oh = Ah; }
        k_level<<<P / 32, 256, 0, stream>>>(ic, ih, gth, oc, oh, WpT, tab, op_idx, start, mshift);
    }

    k_and  <<<64, 128, 0, stream>>>(Ac, Ah, W_and, b_and, c2, h2);
    k_final<<<1, 128, 0, stream>>>(c2, h2, init_emb, W_oend, b_oend, out);
}

// Round 3
// 263.041 us; speedup vs baseline: 3.4135x; 1.5177x over previous
//
#include <hip/hip_runtime.h>

#define NNODES 50000

typedef _Float16 half8 __attribute__((ext_vector_type(8)));
typedef float f32x4 __attribute__((ext_vector_type(4)));

__device__ __forceinline__ float sigm(float x)   { return 1.f / (1.f + __expf(-x)); }
__device__ __forceinline__ float tanh_f(float x) { float e = __expf(2.f * x); return 1.f - 2.f / (e + 1.f); }

// ---------------------------------------------------------------------------
// WpT[512 cols][288 k] fp16. k<128: W_child[2g][k][d]; k<256: W_child[2g+1][k-128][d]
// (col c -> gate g=c>>7, d=c&127). k in 256..287 filled by k_prep_table (op tab).
__global__ __launch_bounds__(256) void k_prep_wpT(const float* __restrict__ Wc,
                                                  _Float16* __restrict__ WpT) {
    int i = blockIdx.x * 256 + threadIdx.x;      // 0..131071
    int c = i >> 8, k = i & 255;
    int g = c >> 7, d = c & 127;
    float v = (k < 128) ? Wc[(2 * g) * 16384 + k * 128 + d]
                        : Wc[(2 * g + 1) * 16384 + (k - 128) * 128 + d];
    WpT[c * 288 + k] = (_Float16)v;
}

// tab rows of WpT: WpT[c*288 + 256 + t] = char_emb[t]@W_x[gx] + b_x[gx] + b_child[2g] + b_child[2g+1]
__global__ __launch_bounds__(256) void k_prep_table(const float* __restrict__ ce,
                                                    const float* __restrict__ Wx,
                                                    const float* __restrict__ bx,
                                                    const float* __restrict__ bc,
                                                    _Float16* __restrict__ WpT) {
    int i = blockIdx.x * 256 + threadIdx.x;      // 0..16383
    int tt = i >> 9, c = i & 511;
    int g = c >> 7, d = c & 127;
    int gx = (g == 0) ? 0 : ((g == 3) ? 2 : 1);
    float acc = bx[gx * 128 + d] + bc[(2 * g) * 128 + d] + bc[(2 * g + 1) * 128 + d];
    const float* x = ce + tt * 128;
    const float* w = Wx + gx * 16384 + d;
    for (int l = 0; l < 128; ++l) acc += x[l] * w[l * 128];
    WpT[c * 288 + 256 + tt] = (_Float16)acc;
}

// WlT[256 cols][128 k] fp16
__global__ __launch_bounds__(256) void k_prep_wlT(const float* __restrict__ Wl,
                                                  _Float16* __restrict__ WlT) {
    int i = blockIdx.x * 256 + threadIdx.x;      // 0..32767
    int c = i >> 7, k = i & 127;
    WlT[i] = (_Float16)Wl[(c >> 7) * 16384 + k * 128 + (c & 127)];
}

// ---------------------------------------------------------------------------
// Leaf tables: [50000 x 128] fp32 -> c_tab fp16, h_tab fp16 via f16 MFMA
__global__ __launch_bounds__(256) void k_prep_nodes(const float* __restrict__ ne,
                                                    const _Float16* __restrict__ WlT,
                                                    const float* __restrict__ bl,
                                                    _Float16* __restrict__ c_tab,
                                                    _Float16* __restrict__ h_tab) {
    const int t = threadIdx.x;
    const int w = t >> 6, l = t & 63;
    const int lr = l & 15, lq = l >> 4;
    const int nb = blockIdx.x * 32;

    int arow[2];
#pragma unroll
    for (int rt = 0; rt < 2; ++rt) {
        int r = nb + rt * 16 + lr;
        arow[rt] = (r < NNODES) ? r : (NNODES - 1);
    }

    f32x4 acc[2][2][2];
#pragma unroll
    for (int rt = 0; rt < 2; ++rt)
#pragma unroll
        for (int g = 0; g < 2; ++g)
#pragma unroll
            for (int ti = 0; ti < 2; ++ti) acc[rt][g][ti] = (f32x4)0.f;

#pragma unroll
    for (int kk = 0; kk < 4; ++kk) {
        half8 af[2];
#pragma unroll
        for (int rt = 0; rt < 2; ++rt) {
            const float* src = ne + (size_t)arow[rt] * 128 + kk * 32 + lq * 8;
            float4 f0 = *(const float4*)src;
            float4 f1 = *(const float4*)(src + 4);
            half8 v;
            v[0] = (_Float16)f0.x; v[1] = (_Float16)f0.y; v[2] = (_Float16)f0.z; v[3] = (_Float16)f0.w;
            v[4] = (_Float16)f1.x; v[5] = (_Float16)f1.y; v[6] = (_Float16)f1.z; v[7] = (_Float16)f1.w;
            af[rt] = v;
        }
#pragma unroll
        for (int g = 0; g < 2; ++g)
#pragma unroll
            for (int ti = 0; ti < 2; ++ti) {
                int col = g * 128 + w * 32 + ti * 16 + lr;
                half8 bb = *(const half8*)(WlT + col * 128 + kk * 32 + lq * 8);
#pragma unroll
                for (int rt = 0; rt < 2; ++rt)
                    acc[rt][g][ti] = __builtin_amdgcn_mfma_f32_16x16x32_f16(af[rt], bb, acc[rt][g][ti], 0, 0, 0);
            }
    }

#pragma unroll
    for (int rt = 0; rt < 2; ++rt)
#pragma unroll
        for (int j = 0; j < 4; ++j) {
            int r = nb + rt * 16 + lq * 4 + j;
            if (r < NNODES) {
#pragma unroll
                for (int ti = 0; ti < 2; ++ti) {
                    int d = w * 32 + ti * 16 + lr;
                    float cc = acc[rt][0][ti][j] + bl[d];
                    float hp = acc[rt][1][ti][j] + bl[128 + d];
                    c_tab[(size_t)r * 128 + d] = (_Float16)cc;
                    h_tab[(size_t)r * 128 + d] = (_Float16)(sigm(hp) * tanh_f(cc));
                }
            }
        }
}

// ---------------------------------------------------------------------------
// k_lo: levels 0-2 fused. 1024 blocks = 64 trees x 16 segs; block owns
// 64 L0-pairs -> 32 L1 -> 16 L2 outputs (written to g2c/g2h).
__global__ __launch_bounds__(256, 2) void k_lo(const _Float16* __restrict__ c_tab,
                                               const _Float16* __restrict__ h_tab,
                                               const int* __restrict__ leaf_idx,
                                               const int* __restrict__ op_idx,
                                               const _Float16* __restrict__ WpT,
                                               float* __restrict__ g2c,
                                               _Float16* __restrict__ g2h) {
    __shared__ int s_leaf[128];
    __shared__ int s_op[112];
    __shared__ _Float16 s_cst[128 * 128];   // staged child-c rows; later h1(32*128)+c1(32*132)
    __shared__ _Float16 s_h0[64 * 128];     // swizzled
    __shared__ _Float16 s_c0[64 * 132];
    _Float16* s_h1 = s_cst;
    _Float16* s_c1 = s_cst + 32 * 128;

    const int t = threadIdx.x;
    const int w = t >> 6, l = t & 63, lr = l & 15, lq = l >> 4;
    const int ks = blockIdx.x >> 4, seg = blockIdx.x & 15;

    if (t < 128) s_leaf[t] = leaf_idx[ks * 2048 + seg * 128 + t];
    else if (t < 192) s_op[t - 128] = op_idx[ks * 2047 + seg * 64 + (t - 128)];
    else if (t < 224) s_op[64 + t - 192] = op_idx[ks * 2047 + 1024 + seg * 32 + (t - 192)];
    else if (t < 240) s_op[96 + t - 224] = op_idx[ks * 2047 + 1536 + seg * 16 + (t - 224)];
    __syncthreads();

    // hoisted gather rows / ops for level 0
    int growL[4], growR[4], opv[4];
#pragma unroll
    for (int rt = 0; rt < 4; ++rt) {
        growL[rt] = s_leaf[2 * (rt * 16 + lr)];
        growR[rt] = s_leaf[2 * (rt * 16 + lr) + 1];
        opv[rt]   = s_op[rt * 16 + lr];
    }

    // stage child-c rows into LDS (latency overlapped with GEMM by early issue)
    {
        half8 stg[8];
#pragma unroll
        for (int i = 0; i < 8; ++i) {
            int idx = i * 256 + t;
            int row = idx >> 4, kb = idx & 15;
            stg[i] = *(const half8*)(c_tab + (size_t)s_leaf[row] * 128 + kb * 8);
        }
#pragma unroll
        for (int i = 0; i < 8; ++i)
            *(half8*)(s_cst + (i * 256 + t) * 8) = stg[i];
    }

    // ---- level 0 GEMM (4 row-tiles, K=288 incl. one-hot op tail) ----
    f32x4 acc[4][4][2];
#pragma unroll
    for (int rt = 0; rt < 4; ++rt)
#pragma unroll
        for (int g = 0; g < 4; ++g)
#pragma unroll
            for (int ti = 0; ti < 2; ++ti) acc[rt][g][ti] = (f32x4)0.f;

#pragma unroll
    for (int kk = 0; kk < 9; ++kk) {
        half8 bb[4][2];
#pragma unroll
        for (int g = 0; g < 4; ++g)
#pragma unroll
            for (int ti = 0; ti < 2; ++ti)
                bb[g][ti] = *(const half8*)(WpT + (g * 128 + w * 32 + ti * 16 + lr) * 288 + kk * 32 + lq * 8);
        half8 af[4];
        if (kk < 8) {
            int ko = (kk & 3) * 32 + lq * 8;
#pragma unroll
            for (int rt = 0; rt < 4; ++rt) {
                int grow = (kk < 4) ? growL[rt] : growR[rt];
                af[rt] = *(const half8*)(h_tab + (size_t)grow * 128 + ko);
            }
        } else {
#pragma unroll
            for (int rt = 0; rt < 4; ++rt)
#pragma unroll
                for (int i = 0; i < 8; ++i)
                    af[rt][i] = (_Float16)((lq * 8 + i) == opv[rt] ? 1.f : 0.f);
        }
#pragma unroll
        for (int rt = 0; rt < 4; ++rt)
#pragma unroll
            for (int g = 0; g < 4; ++g)
#pragma unroll
                for (int ti = 0; ti < 2; ++ti)
                    acc[rt][g][ti] = __builtin_amdgcn_mfma_f32_16x16x32_f16(af[rt], bb[g][ti], acc[rt][g][ti], 0, 0, 0);
    }
    __syncthreads();

    // ---- level 0 epilogue -> s_h0 (swz), s_c0 ----
#pragma unroll
    for (int rt = 0; rt < 4; ++rt)
#pragma unroll
        for (int j = 0; j < 4; ++j) {
            int p = rt * 16 + lq * 4 + j;
#pragma unroll
            for (int ti = 0; ti < 2; ++ti) {
                int d = w * 32 + ti * 16 + lr;
                float vi = acc[rt][0][ti][j], vl = acc[rt][1][ti][j];
                float vr = acc[rt][2][ti][j], vu = acc[rt][3][ti][j];
                float lc = (float)s_cst[(2 * p) * 128 + d];
                float rc = (float)s_cst[(2 * p + 1) * 128 + d];
                float cc = sigm(vi) * tanh_f(vu) + sigm(vl) * lc + sigm(vr) * rc;
                s_c0[p * 132 + d] = (_Float16)cc;
                s_h0[p * 128 + (d ^ ((p & 15) << 3))] = (_Float16)tanh_f(cc);
            }
        }
    __syncthreads();

    // ---- level 1 GEMM (2 row-tiles) ----
    f32x4 acc1[2][4][2];
#pragma unroll
    for (int rt = 0; rt < 2; ++rt)
#pragma unroll
        for (int g = 0; g < 4; ++g)
#pragma unroll
            for (int ti = 0; ti < 2; ++ti) acc1[rt][g][ti] = (f32x4)0.f;

#pragma unroll
    for (int kk = 0; kk < 9; ++kk) {
        half8 bb[4][2];
#pragma unroll
        for (int g = 0; g < 4; ++g)
#pragma unroll
            for (int ti = 0; ti < 2; ++ti)
                bb[g][ti] = *(const half8*)(WpT + (g * 128 + w * 32 + ti * 16 + lr) * 288 + kk * 32 + lq * 8);
        half8 af[2];
        if (kk < 8) {
            int side = kk >> 2, ko = (kk & 3) * 32 + lq * 8;
#pragma unroll
            for (int rt = 0; rt < 2; ++rt) {
                int child = 2 * (rt * 16 + lr) + side;
                af[rt] = *(const half8*)(s_h0 + child * 128 + (ko ^ ((child & 15) << 3)));
            }
        } else {
#pragma unroll
            for (int rt = 0; rt < 2; ++rt) {
                int op = s_op[64 + rt * 16 + lr];
#pragma unroll
                for (int i = 0; i < 8; ++i)
                    af[rt][i] = (_Float16)((lq * 8 + i) == op ? 1.f : 0.f);
            }
        }
#pragma unroll
        for (int rt = 0; rt < 2; ++rt)
#pragma unroll
            for (int g = 0; g < 4; ++g)
#pragma unroll
                for (int ti = 0; ti < 2; ++ti)
                    acc1[rt][g][ti] = __builtin_amdgcn_mfma_f32_16x16x32_f16(af[rt], bb[g][ti], acc1[rt][g][ti], 0, 0, 0);
    }

    // ---- level 1 epilogue -> s_h1/s_c1 (alias of s_cst; s_cst dead) ----
#pragma unroll
    for (int rt = 0; rt < 2; ++rt)
#pragma unroll
        for (int j = 0; j < 4; ++j) {
            int p = rt * 16 + lq * 4 + j;
#pragma unroll
            for (int ti = 0; ti < 2; ++ti) {
                int d = w * 32 + ti * 16 + lr;
                float vi = acc1[rt][0][ti][j], vl = acc1[rt][1][ti][j];
                float vr = acc1[rt][2][ti][j], vu = acc1[rt][3][ti][j];
                float lc = (float)s_c0[(2 * p) * 132 + d];
                float rc = (float)s_c0[(2 * p + 1) * 132 + d];
                float cc = sigm(vi) * tanh_f(vu) + sigm(vl) * lc + sigm(vr) * rc;
                s_c1[p * 132 + d] = (_Float16)cc;
                s_h1[p * 128 + (d ^ ((p & 15) << 3))] = (_Float16)tanh_f(cc);
            }
        }
    __syncthreads();

    // ---- level 2 GEMM (1 row-tile) + epilogue -> global ----
    f32x4 acc2[4][2];
#pragma unroll
    for (int g = 0; g < 4; ++g)
#pragma unroll
        for (int ti = 0; ti < 2; ++ti) acc2[g][ti] = (f32x4)0.f;

#pragma unroll
    for (int kk = 0; kk < 9; ++kk) {
        half8 bb[4][2];
#pragma unroll
        for (int g = 0; g < 4; ++g)
#pragma unroll
            for (int ti = 0; ti < 2; ++ti)
                bb[g][ti] = *(const half8*)(WpT + (g * 128 + w * 32 + ti * 16 + lr) * 288 + kk * 32 + lq * 8);
        half8 a;
        if (kk < 8) {
            int side = kk >> 2, ko = (kk & 3) * 32 + lq * 8;
            int child = 2 * lr + side;
            a = *(const half8*)(s_h1 + child * 128 + (ko ^ ((child & 15) << 3)));
        } else {
            int op = s_op[96 + lr];
#pragma unroll
            for (int i = 0; i < 8; ++i)
                a[i] = (_Float16)((lq * 8 + i) == op ? 1.f : 0.f);
        }
#pragma unroll
        for (int g = 0; g < 4; ++g)
#pragma unroll
            for (int ti = 0; ti < 2; ++ti)
                acc2[g][ti] = __builtin_amdgcn_mfma_f32_16x16x32_f16(a, bb[g][ti], acc2[g][ti], 0, 0, 0);
    }

#pragma unroll
    for (int j = 0; j < 4; ++j) {
        int p = lq * 4 + j;
#pragma unroll
        for (int ti = 0; ti < 2; ++ti) {
            int d = w * 32 + ti * 16 + lr;
            float vi = acc2[0][ti][j], vl = acc2[1][ti][j];
            float vr = acc2[2][ti][j], vu = acc2[3][ti][j];
            float lc = (float)s_c1[(2 * p) * 132 + d];
            float rc = (float)s_c1[(2 * p + 1) * 132 + d];
            float cc = sigm(vi) * tanh_f(vu) + sigm(vl) * lc + sigm(vr) * rc;
            size_t orow = (size_t)blockIdx.x * 16 + p;
            g2c[orow * 128 + d] = cc;
            g2h[orow * 128 + d] = (_Float16)tanh_f(cc);
        }
    }
}

// ---------------------------------------------------------------------------
// k_hi: levels 3-10 + AND projection. One block per tree.
template <int NRT, bool GSRC>
__device__ __forceinline__ void level_pass(int np, int pass0, int opoff,
                                           const _Float16* hS, const _Float16* cS,
                                           const float* __restrict__ gc,
                                           const _Float16* __restrict__ gh, int rowbase,
                                           _Float16* hD, _Float16* cD,
                                           const _Float16* __restrict__ WpT,
                                           const int* s_op, int w, int lq, int lr) {
    f32x4 acc[NRT][4][2];
#pragma unroll
    for (int rt = 0; rt < NRT; ++rt)
#pragma unroll
        for (int g = 0; g < 4; ++g)
#pragma unroll
            for (int ti = 0; ti < 2; ++ti) acc[rt][g][ti] = (f32x4)0.f;

#pragma unroll
    for (int kk = 0; kk < 9; ++kk) {
        half8 bb[4][2];
#pragma unroll
        for (int g = 0; g < 4; ++g)
#pragma unroll
            for (int ti = 0; ti < 2; ++ti)
                bb[g][ti] = *(const half8*)(WpT + (g * 128 + w * 32 + ti * 16 + lr) * 288 + kk * 32 + lq * 8);
        half8 af[NRT];
        if (kk < 8) {
            int side = kk >> 2, ko = (kk & 3) * 32 + lq * 8;
#pragma unroll
            for (int rt = 0; rt < NRT; ++rt) {
                int pidx = pass0 + rt * 16 + lr; if (pidx > np - 1) pidx = np - 1;
                int child = 2 * pidx + side;
                if constexpr (GSRC)
                    af[rt] = *(const half8*)(gh + (size_t)(rowbase + child) * 128 + ko);
                else
                    af[rt] = *(const half8*)(hS + child * 128 + (ko ^ ((child & 15) << 3)));
            }
        } else {
#pragma unroll
            for (int rt = 0; rt < NRT; ++rt) {
                int pidx = pass0 + rt * 16 + lr; if (pidx > np - 1) pidx = np - 1;
                int op = s_op[opoff + pidx];
#pragma unroll
                for (int i = 0; i < 8; ++i)
                    af[rt][i] = (_Float16)((lq * 8 + i) == op ? 1.f : 0.f);
            }
        }
#pragma unroll
        for (int rt = 0; rt < NRT; ++rt)
#pragma unroll
            for (int g = 0; g < 4; ++g)
#pragma unroll
                for (int ti = 0; ti < 2; ++ti)
                    acc[rt][g][ti] = __builtin_amdgcn_mfma_f32_16x16x32_f16(af[rt], bb[g][ti], acc[rt][g][ti], 0, 0, 0);
    }

#pragma unroll
    for (int rt = 0; rt < NRT; ++rt)
#pragma unroll
        for (int j = 0; j < 4; ++j) {
            int p = pass0 + rt * 16 + lq * 4 + j;
            if (p < np) {
#pragma unroll
                for (int ti = 0; ti < 2; ++ti) {
                    int dcol = w * 32 + ti * 16 + lr;
                    float vi = acc[rt][0][ti][j], vl = acc[rt][1][ti][j];
                    float vr = acc[rt][2][ti][j], vu = acc[rt][3][ti][j];
                    float lc, rc;
                    if constexpr (GSRC) {
                        lc = gc[(size_t)(rowbase + 2 * p) * 128 + dcol];
                        rc = gc[(size_t)(rowbase + 2 * p + 1) * 128 + dcol];
                    } else {
                        lc = (float)cS[(2 * p) * 132 + dcol];
                        rc = (float)cS[(2 * p + 1) * 132 + dcol];
                    }
                    float cc = sigm(vi) * tanh_f(vu) + sigm(vl) * lc + sigm(vr) * rc;
                    cD[p * 132 + dcol] = (_Float16)cc;
                    hD[p * 128 + (dcol ^ ((p & 15) << 3))] = (_Float16)tanh_f(cc);
                }
            }
        }
}

__global__ __launch_bounds__(256, 1) void k_hi(const float* __restrict__ g2c,
                                               const _Float16* __restrict__ g2h,
                                               const int* __restrict__ op_idx,
                                               const _Float16* __restrict__ WpT,
                                               const float* __restrict__ Wa,
                                               const float* __restrict__ ba,
                                               float* __restrict__ c2,
                                               float* __restrict__ h2) {
    __shared__ int s_op[256];
    __shared__ _Float16 hA[128 * 128], cA[128 * 132];
    __shared__ _Float16 hB[64 * 128],  cB[64 * 132];
    const int t = threadIdx.x, w = t >> 6, l = t & 63, lr = l & 15, lq = l >> 4;
    const int tree = blockIdx.x;

    if (t < 255) s_op[t] = op_idx[tree * 2047 + 1792 + t];
    __syncthreads();

    // d=3 (np=128, global src, 2 passes)
    level_pass<4, true>(128, 0,  0, nullptr, nullptr, g2c, g2h, tree * 256, hA, cA, WpT, s_op, w, lq, lr);
    level_pass<4, true>(128, 64, 0, nullptr, nullptr, g2c, g2h, tree * 256, hA, cA, WpT, s_op, w, lq, lr);
    __syncthreads();
    level_pass<4, false>(64, 0, 128, hA, cA, nullptr, nullptr, 0, hB, cB, WpT, s_op, w, lq, lr);
    __syncthreads();
    level_pass<2, false>(32, 0, 192, hB, cB, nullptr, nullptr, 0, hA, cA, WpT, s_op, w, lq, lr);
    __syncthreads();
    level_pass<1, false>(16, 0, 224, hA, cA, nullptr, nullptr, 0, hB, cB, WpT, s_op, w, lq, lr);
    __syncthreads();
    level_pass<1, false>(8, 0, 240, hB, cB, nullptr, nullptr, 0, hA, cA, WpT, s_op, w, lq, lr);
    __syncthreads();
    level_pass<1, false>(4, 0, 248, hA, cA, nullptr, nullptr, 0, hB, cB, WpT, s_op, w, lq, lr);
    __syncthreads();
    level_pass<1, false>(2, 0, 252, hB, cB, nullptr, nullptr, 0, hA, cA, WpT, s_op, w, lq, lr);
    __syncthreads();
    level_pass<1, false>(1, 0, 254, hA, cA, nullptr, nullptr, 0, hB, cB, WpT, s_op, w, lq, lr);
    __syncthreads();

    // AND projection: root is row 0 of B buffers
    {
        int dd = t & 127;
        if (t < 128) {
            float a = ba[dd];
            for (int ll = 0; ll < 128; ++ll) a += (float)cB[ll] * Wa[ll * 128 + dd];
            c2[tree * 128 + dd] = a;
        } else {
            float a = ba[128 + dd];
            for (int ll = 0; ll < 128; ++ll) a += (float)hB[ll] * Wa[16384 + ll * 128 + dd];
            h2[tree * 128 + dd] = a;
        }
    }
}

// ---------------------------------------------------------------------------
__global__ __launch_bounds__(128) void k_final(const float* __restrict__ c2,
                                               const float* __restrict__ h2,
                                               const float* __restrict__ init_e,
                                               const float* __restrict__ Wo,
                                               const float* __restrict__ bo,
                                               float* __restrict__ out) {
    __shared__ float s[384];
    const int d = threadIdx.x;
    float cm = c2[d], hm = h2[d];
    for (int k = 1; k < 64; ++k) {
        cm = fminf(cm, c2[k * 128 + d]);
        hm = fminf(hm, h2[k * 128 + d]);
    }
    s[d] = init_e[d];
    s[128 + d] = cm;
    s[256 + d] = hm;
    __syncthreads();
    float a = bo[d];
    for (int l = 0; l < 384; ++l) a += s[l] * Wo[l * 128 + d];
    out[d] = tanhf(a);
}

// ---------------------------------------------------------------------------
extern "C" void kernel_launch(void* const* d_in, const int* in_sizes, int n_in,
                              void* d_out, int out_size, void* d_ws, size_t ws_size,
                              hipStream_t stream) {
    const float* node_emb = (const float*)d_in[0];
    const float* init_emb = (const float*)d_in[1];
    const float* char_emb = (const float*)d_in[2];
    const float* W_child  = (const float*)d_in[3];
    const float* b_child  = (const float*)d_in[4];
    const float* W_x      = (const float*)d_in[5];
    const float* b_x      = (const float*)d_in[6];
    const float* W_leaf   = (const float*)d_in[7];
    const float* b_leaf   = (const float*)d_in[8];
    const float* W_and    = (const float*)d_in[9];
    const float* b_and    = (const float*)d_in[10];
    const float* W_oend   = (const float*)d_in[11];
    const float* b_oend   = (const float*)d_in[12];
    const int* leaf_idx   = (const int*)d_in[13];
    const int* op_idx     = (const int*)d_in[14];
    float* out = (float*)d_out;
    (void)in_sizes; (void)n_in; (void)out_size; (void)ws_size;

    char* p = (char*)d_ws;
    auto carve = [&](size_t bytes) { char* r = p; p += (bytes + 255) & ~255ull; return r; };
    _Float16* WpT   = (_Float16*)carve((size_t)512 * 288 * 2);
    _Float16* WlT   = (_Float16*)carve((size_t)256 * 128 * 2);
    _Float16* c_tab = (_Float16*)carve((size_t)NNODES * 128 * 2);
    _Float16* h_tab = (_Float16*)carve((size_t)NNODES * 128 * 2);
    float*    g2c   = (float*)carve((size_t)16384 * 128 * 4);
    _Float16* g2h   = (_Float16*)carve((size_t)16384 * 128 * 2);
    float*    c2    = (float*)carve(64 * 128 * 4);
    float*    h2    = (float*)carve(64 * 128 * 4);

    k_prep_wpT  <<<512, 256, 0, stream>>>(W_child, WpT);
    k_prep_wlT  <<<128, 256, 0, stream>>>(W_leaf, WlT);
    k_prep_table<<<64, 256, 0, stream>>>(char_emb, W_x, b_x, b_child, WpT);
    k_prep_nodes<<<(NNODES + 31) / 32, 256, 0, stream>>>(node_emb, WlT, b_leaf, c_tab, h_tab);
    k_lo <<<1024, 256, 0, stream>>>(c_tab, h_tab, leaf_idx, op_idx, WpT, g2c, g2h);
    k_hi <<<64, 256, 0, stream>>>(g2c, g2h, op_idx, WpT, W_and, b_and, c2, h2);
    k_final<<<1, 128, 0, stream>>>(c2, h2, init_emb, W_oend, b_oend, out);
}

// Round 4
// 261.644 us; speedup vs baseline: 3.4317x; 1.0053x over previous
//
#include <hip/hip_runtime.h>

#define NNODES 50000

typedef _Float16 half8 __attribute__((ext_vector_type(8)));
typedef float f32x4 __attribute__((ext_vector_type(4)));

__device__ __forceinline__ float sigm(float x)   { return 1.f / (1.f + __expf(-x)); }
__device__ __forceinline__ float tanh_f(float x) { float e = __expf(2.f * x); return 1.f - 2.f / (e + 1.f); }

// ---------------------------------------------------------------------------
// WpT[512 cols][288 k] fp16. k<128: W_child[2g][k][d]; k<256: W_child[2g+1][k-128][d]
// (col c -> gate g=c>>7, d=c&127). k in 256..287 filled by k_prep_table (op tab).
__global__ __launch_bounds__(256) void k_prep_wpT(const float* __restrict__ Wc,
                                                  _Float16* __restrict__ WpT) {
    int i = blockIdx.x * 256 + threadIdx.x;      // 0..131071
    int c = i >> 8, k = i & 255;
    int g = c >> 7, d = c & 127;
    float v = (k < 128) ? Wc[(2 * g) * 16384 + k * 128 + d]
                        : Wc[(2 * g + 1) * 16384 + (k - 128) * 128 + d];
    WpT[c * 288 + k] = (_Float16)v;
}

// tab rows of WpT: WpT[c*288 + 256 + t] = char_emb[t]@W_x[gx] + b_x[gx] + b_child[2g] + b_child[2g+1]
__global__ __launch_bounds__(256) void k_prep_table(const float* __restrict__ ce,
                                                    const float* __restrict__ Wx,
                                                    const float* __restrict__ bx,
                                                    const float* __restrict__ bc,
                                                    _Float16* __restrict__ WpT) {
    int i = blockIdx.x * 256 + threadIdx.x;      // 0..16383
    int tt = i >> 9, c = i & 511;
    int g = c >> 7, d = c & 127;
    int gx = (g == 0) ? 0 : ((g == 3) ? 2 : 1);
    float acc = bx[gx * 128 + d] + bc[(2 * g) * 128 + d] + bc[(2 * g + 1) * 128 + d];
    const float* x = ce + tt * 128;
    const float* w = Wx + gx * 16384 + d;
    for (int l = 0; l < 128; ++l) acc += x[l] * w[l * 128];
    WpT[c * 288 + 256 + tt] = (_Float16)acc;
}

// WlT[256 cols][128 k] fp16
__global__ __launch_bounds__(256) void k_prep_wlT(const float* __restrict__ Wl,
                                                  _Float16* __restrict__ WlT) {
    int i = blockIdx.x * 256 + threadIdx.x;      // 0..32767
    int c = i >> 7, k = i & 127;
    WlT[i] = (_Float16)Wl[(c >> 7) * 16384 + k * 128 + (c & 127)];
}

// ---------------------------------------------------------------------------
// Leaf tables: [50000 x 128] fp32 -> c_tab fp16, h_tab fp16 via f16 MFMA
__global__ __launch_bounds__(256) void k_prep_nodes(const float* __restrict__ ne,
                                                    const _Float16* __restrict__ WlT,
                                                    const float* __restrict__ bl,
                                                    _Float16* __restrict__ c_tab,
                                                    _Float16* __restrict__ h_tab) {
    const int t = threadIdx.x;
    const int w = t >> 6, l = t & 63;
    const int lr = l & 15, lq = l >> 4;
    const int nb = blockIdx.x * 32;

    int arow[2];
#pragma unroll
    for (int rt = 0; rt < 2; ++rt) {
        int r = nb + rt * 16 + lr;
        arow[rt] = (r < NNODES) ? r : (NNODES - 1);
    }

    f32x4 acc[2][2][2];
#pragma unroll
    for (int rt = 0; rt < 2; ++rt)
#pragma unroll
        for (int g = 0; g < 2; ++g)
#pragma unroll
            for (int ti = 0; ti < 2; ++ti) acc[rt][g][ti] = (f32x4)0.f;

#pragma unroll
    for (int kk = 0; kk < 4; ++kk) {
        half8 af[2];
#pragma unroll
        for (int rt = 0; rt < 2; ++rt) {
            const float* src = ne + (size_t)arow[rt] * 128 + kk * 32 + lq * 8;
            float4 f0 = *(const float4*)src;
            float4 f1 = *(const float4*)(src + 4);
            half8 v;
            v[0] = (_Float16)f0.x; v[1] = (_Float16)f0.y; v[2] = (_Float16)f0.z; v[3] = (_Float16)f0.w;
            v[4] = (_Float16)f1.x; v[5] = (_Float16)f1.y; v[6] = (_Float16)f1.z; v[7] = (_Float16)f1.w;
            af[rt] = v;
        }
#pragma unroll
        for (int g = 0; g < 2; ++g)
#pragma unroll
            for (int ti = 0; ti < 2; ++ti) {
                int col = g * 128 + w * 32 + ti * 16 + lr;
                half8 bb = *(const half8*)(WlT + col * 128 + kk * 32 + lq * 8);
#pragma unroll
                for (int rt = 0; rt < 2; ++rt)
                    acc[rt][g][ti] = __builtin_amdgcn_mfma_f32_16x16x32_f16(af[rt], bb, acc[rt][g][ti], 0, 0, 0);
            }
    }

#pragma unroll
    for (int rt = 0; rt < 2; ++rt)
#pragma unroll
        for (int j = 0; j < 4; ++j) {
            int r = nb + rt * 16 + lq * 4 + j;
            if (r < NNODES) {
#pragma unroll
                for (int ti = 0; ti < 2; ++ti) {
                    int d = w * 32 + ti * 16 + lr;
                    float cc = acc[rt][0][ti][j] + bl[d];
                    float hp = acc[rt][1][ti][j] + bl[128 + d];
                    c_tab[(size_t)r * 128 + d] = (_Float16)cc;
                    h_tab[(size_t)r * 128 + d] = (_Float16)(sigm(hp) * tanh_f(cc));
                }
            }
        }
}

// ---------------------------------------------------------------------------
// k_lo: levels 0-2 fused. 1024 blocks = 64 trees x 16 segs; block owns
// 64 L0-pairs -> 32 L1 -> 16 L2 outputs. Level 0 in two 32-pair half-passes
// with register-staged gathers (T14 async-split) for deep MLP.
__global__ __launch_bounds__(256, 2) void k_lo(const _Float16* __restrict__ c_tab,
                                               const _Float16* __restrict__ h_tab,
                                               const int* __restrict__ leaf_idx,
                                               const int* __restrict__ op_idx,
                                               const _Float16* __restrict__ WpT,
                                               float* __restrict__ g2c,
                                               _Float16* __restrict__ g2h) {
    __shared__ int s_leaf[128];
    __shared__ int s_op[112];
    __shared__ _Float16 s_cst[64 * 132];    // staged child-c rows (one half); reused as h1|c1
    __shared__ _Float16 s_h0[64 * 128];     // swizzled
    __shared__ _Float16 s_c0[64 * 132];
    _Float16* s_h1 = s_cst;                 // 32*128
    _Float16* s_c1 = s_cst + 32 * 128;      // 32*132 (8320 <= 8448)

    const int t = threadIdx.x;
    const int w = t >> 6, l = t & 63, lr = l & 15, lq = l >> 4;
    const int ks = blockIdx.x >> 4, seg = blockIdx.x & 15;
    const int crow = t >> 2, coff = (t & 3) * 32;

    if (t < 128) s_leaf[t] = leaf_idx[ks * 2048 + seg * 128 + t];
    else if (t < 192) s_op[t - 128] = op_idx[ks * 2047 + seg * 64 + (t - 128)];
    else if (t < 224) s_op[64 + t - 192] = op_idx[ks * 2047 + 1024 + seg * 32 + (t - 192)];
    else if (t < 240) s_op[96 + t - 224] = op_idx[ks * 2047 + 1536 + seg * 16 + (t - 224)];
    __syncthreads();

    // ---- half 0: issue c-stage + A-gathers into registers ----
    half8 cr0[4];
    {
        const _Float16* src = c_tab + (size_t)s_leaf[crow] * 128 + coff;
#pragma unroll
        for (int i = 0; i < 4; ++i) cr0[i] = *(const half8*)(src + i * 8);
    }
    int opv0[2];
    half8 af0[2][8];
#pragma unroll
    for (int rt = 0; rt < 2; ++rt) {
        int pg = rt * 16 + lr;
        int gl = s_leaf[2 * pg], gr = s_leaf[2 * pg + 1];
        opv0[rt] = s_op[pg];
#pragma unroll
        for (int kk = 0; kk < 8; ++kk) {
            int row = (kk < 4) ? gl : gr;
            af0[rt][kk] = *(const half8*)(h_tab + (size_t)row * 128 + (kk & 3) * 32 + lq * 8);
        }
    }

    // ---- GEMM half 0 ----
    f32x4 acc[2][4][2];
#pragma unroll
    for (int rt = 0; rt < 2; ++rt)
#pragma unroll
        for (int g = 0; g < 4; ++g)
#pragma unroll
            for (int ti = 0; ti < 2; ++ti) acc[rt][g][ti] = (f32x4)0.f;

#pragma unroll
    for (int kk = 0; kk < 9; ++kk) {
        half8 bb[4][2];
#pragma unroll
        for (int g = 0; g < 4; ++g)
#pragma unroll
            for (int ti = 0; ti < 2; ++ti)
                bb[g][ti] = *(const half8*)(WpT + (g * 128 + w * 32 + ti * 16 + lr) * 288 + kk * 32 + lq * 8);
        half8 a[2];
        if (kk < 8) {
            a[0] = af0[0][kk]; a[1] = af0[1][kk];
        } else {
#pragma unroll
            for (int rt = 0; rt < 2; ++rt)
#pragma unroll
                for (int i = 0; i < 8; ++i)
                    a[rt][i] = (_Float16)((lq * 8 + i) == opv0[rt] ? 1.f : 0.f);
        }
#pragma unroll
        for (int rt = 0; rt < 2; ++rt)
#pragma unroll
            for (int g = 0; g < 4; ++g)
#pragma unroll
                for (int ti = 0; ti < 2; ++ti)
                    acc[rt][g][ti] = __builtin_amdgcn_mfma_f32_16x16x32_f16(a[rt], bb[g][ti], acc[rt][g][ti], 0, 0, 0);
    }

    // ---- issue half-1 c-stage + A-gathers (latency hidden under epilogue 0) ----
    half8 cr1[4];
    {
        const _Float16* src = c_tab + (size_t)s_leaf[64 + crow] * 128 + coff;
#pragma unroll
        for (int i = 0; i < 4; ++i) cr1[i] = *(const half8*)(src + i * 8);
    }
    int opv1[2];
    half8 af1[2][8];
#pragma unroll
    for (int rt = 0; rt < 2; ++rt) {
        int pg = 32 + rt * 16 + lr;
        int gl = s_leaf[2 * pg], gr = s_leaf[2 * pg + 1];
        opv1[rt] = s_op[pg];
#pragma unroll
        for (int kk = 0; kk < 8; ++kk) {
            int row = (kk < 4) ? gl : gr;
            af1[rt][kk] = *(const half8*)(h_tab + (size_t)row * 128 + (kk & 3) * 32 + lq * 8);
        }
    }

    // ---- write cst0 (loads long since landed), epilogue 0 ----
#pragma unroll
    for (int i = 0; i < 4; ++i) *(half8*)(s_cst + crow * 132 + coff + i * 8) = cr0[i];
    __syncthreads();

#pragma unroll
    for (int rt = 0; rt < 2; ++rt)
#pragma unroll
        for (int j = 0; j < 4; ++j) {
            int pl = rt * 16 + lq * 4 + j;        // == global pair for half 0
#pragma unroll
            for (int ti = 0; ti < 2; ++ti) {
                int d = w * 32 + ti * 16 + lr;
                float vi = acc[rt][0][ti][j], vl = acc[rt][1][ti][j];
                float vr = acc[rt][2][ti][j], vu = acc[rt][3][ti][j];
                float lc = (float)s_cst[(2 * pl) * 132 + d];
                float rc = (float)s_cst[(2 * pl + 1) * 132 + d];
                float cc = sigm(vi) * tanh_f(vu) + sigm(vl) * lc + sigm(vr) * rc;
                s_c0[pl * 132 + d] = (_Float16)cc;
                s_h0[pl * 128 + (d ^ ((pl & 15) << 3))] = (_Float16)tanh_f(cc);
            }
        }
    __syncthreads();   // s_cst reuse guard

    // ---- write cst1, GEMM half 1 ----
#pragma unroll
    for (int i = 0; i < 4; ++i) *(half8*)(s_cst + crow * 132 + coff + i * 8) = cr1[i];

#pragma unroll
    for (int rt = 0; rt < 2; ++rt)
#pragma unroll
        for (int g = 0; g < 4; ++g)
#pragma unroll
            for (int ti = 0; ti < 2; ++ti) acc[rt][g][ti] = (f32x4)0.f;

#pragma unroll
    for (int kk = 0; kk < 9; ++kk) {
        half8 bb[4][2];
#pragma unroll
        for (int g = 0; g < 4; ++g)
#pragma unroll
            for (int ti = 0; ti < 2; ++ti)
                bb[g][ti] = *(const half8*)(WpT + (g * 128 + w * 32 + ti * 16 + lr) * 288 + kk * 32 + lq * 8);
        half8 a[2];
        if (kk < 8) {
            a[0] = af1[0][kk]; a[1] = af1[1][kk];
        } else {
#pragma unroll
            for (int rt = 0; rt < 2; ++rt)
#pragma unroll
                for (int i = 0; i < 8; ++i)
                    a[rt][i] = (_Float16)((lq * 8 + i) == opv1[rt] ? 1.f : 0.f);
        }
#pragma unroll
        for (int rt = 0; rt < 2; ++rt)
#pragma unroll
            for (int g = 0; g < 4; ++g)
#pragma unroll
                for (int ti = 0; ti < 2; ++ti)
                    acc[rt][g][ti] = __builtin_amdgcn_mfma_f32_16x16x32_f16(a[rt], bb[g][ti], acc[rt][g][ti], 0, 0, 0);
    }
    __syncthreads();   // cst1 visible to all

    // ---- epilogue 1 ----
#pragma unroll
    for (int rt = 0; rt < 2; ++rt)
#pragma unroll
        for (int j = 0; j < 4; ++j) {
            int pl = rt * 16 + lq * 4 + j;
            int pg = 32 + pl;
#pragma unroll
            for (int ti = 0; ti < 2; ++ti) {
                int d = w * 32 + ti * 16 + lr;
                float vi = acc[rt][0][ti][j], vl = acc[rt][1][ti][j];
                float vr = acc[rt][2][ti][j], vu = acc[rt][3][ti][j];
                float lc = (float)s_cst[(2 * pl) * 132 + d];
                float rc = (float)s_cst[(2 * pl + 1) * 132 + d];
                float cc = sigm(vi) * tanh_f(vu) + sigm(vl) * lc + sigm(vr) * rc;
                s_c0[pg * 132 + d] = (_Float16)cc;
                s_h0[pg * 128 + (d ^ ((pg & 15) << 3))] = (_Float16)tanh_f(cc);
            }
        }
    __syncthreads();   // h0/c0 complete; s_cst reads done -> h1/c1 alias safe

    // ---- level 1 (32 pairs) ----
#pragma unroll
    for (int rt = 0; rt < 2; ++rt)
#pragma unroll
        for (int g = 0; g < 4; ++g)
#pragma unroll
            for (int ti = 0; ti < 2; ++ti) acc[rt][g][ti] = (f32x4)0.f;

#pragma unroll
    for (int kk = 0; kk < 9; ++kk) {
        half8 bb[4][2];
#pragma unroll
        for (int g = 0; g < 4; ++g)
#pragma unroll
            for (int ti = 0; ti < 2; ++ti)
                bb[g][ti] = *(const half8*)(WpT + (g * 128 + w * 32 + ti * 16 + lr) * 288 + kk * 32 + lq * 8);
        half8 a[2];
        if (kk < 8) {
            int side = kk >> 2, ko = (kk & 3) * 32 + lq * 8;
#pragma unroll
            for (int rt = 0; rt < 2; ++rt) {
                int child = 2 * (rt * 16 + lr) + side;
                a[rt] = *(const half8*)(s_h0 + child * 128 + (ko ^ ((child & 15) << 3)));
            }
        } else {
#pragma unroll
            for (int rt = 0; rt < 2; ++rt) {
                int op = s_op[64 + rt * 16 + lr];
#pragma unroll
                for (int i = 0; i < 8; ++i)
                    a[rt][i] = (_Float16)((lq * 8 + i) == op ? 1.f : 0.f);
            }
        }
#pragma unroll
        for (int rt = 0; rt < 2; ++rt)
#pragma unroll
            for (int g = 0; g < 4; ++g)
#pragma unroll
                for (int ti = 0; ti < 2; ++ti)
                    acc[rt][g][ti] = __builtin_amdgcn_mfma_f32_16x16x32_f16(a[rt], bb[g][ti], acc[rt][g][ti], 0, 0, 0);
    }

#pragma unroll
    for (int rt = 0; rt < 2; ++rt)
#pragma unroll
        for (int j = 0; j < 4; ++j) {
            int pl = rt * 16 + lq * 4 + j;
#pragma unroll
            for (int ti = 0; ti < 2; ++ti) {
                int d = w * 32 + ti * 16 + lr;
                float vi = acc[rt][0][ti][j], vl = acc[rt][1][ti][j];
                float vr = acc[rt][2][ti][j], vu = acc[rt][3][ti][j];
                float lc = (float)s_c0[(2 * pl) * 132 + d];
                float rc = (float)s_c0[(2 * pl + 1) * 132 + d];
                float cc = sigm(vi) * tanh_f(vu) + sigm(vl) * lc + sigm(vr) * rc;
                s_c1[pl * 132 + d] = (_Float16)cc;
                s_h1[pl * 128 + (d ^ ((pl & 15) << 3))] = (_Float16)tanh_f(cc);
            }
        }
    __syncthreads();

    // ---- level 2 (16 pairs) -> global ----
    f32x4 acc2[4][2];
#pragma unroll
    for (int g = 0; g < 4; ++g)
#pragma unroll
        for (int ti = 0; ti < 2; ++ti) acc2[g][ti] = (f32x4)0.f;

#pragma unroll
    for (int kk = 0; kk < 9; ++kk) {
        half8 bb[4][2];
#pragma unroll
        for (int g = 0; g < 4; ++g)
#pragma unroll
            for (int ti = 0; ti < 2; ++ti)
                bb[g][ti] = *(const half8*)(WpT + (g * 128 + w * 32 + ti * 16 + lr) * 288 + kk * 32 + lq * 8);
        half8 a;
        if (kk < 8) {
            int side = kk >> 2, ko = (kk & 3) * 32 + lq * 8;
            int child = 2 * lr + side;
            a = *(const half8*)(s_h1 + child * 128 + (ko ^ ((child & 15) << 3)));
        } else {
            int op = s_op[96 + lr];
#pragma unroll
            for (int i = 0; i < 8; ++i)
                a[i] = (_Float16)((lq * 8 + i) == op ? 1.f : 0.f);
        }
#pragma unroll
        for (int g = 0; g < 4; ++g)
#pragma unroll
            for (int ti = 0; ti < 2; ++ti)
                acc2[g][ti] = __builtin_amdgcn_mfma_f32_16x16x32_f16(a, bb[g][ti], acc2[g][ti], 0, 0, 0);
    }

#pragma unroll
    for (int j = 0; j < 4; ++j) {
        int p = lq * 4 + j;
#pragma unroll
        for (int ti = 0; ti < 2; ++ti) {
            int d = w * 32 + ti * 16 + lr;
            float vi = acc2[0][ti][j], vl = acc2[1][ti][j];
            float vr = acc2[2][ti][j], vu = acc2[3][ti][j];
            float lc = (float)s_c1[(2 * p) * 132 + d];
            float rc = (float)s_c1[(2 * p + 1) * 132 + d];
            float cc = sigm(vi) * tanh_f(vu) + sigm(vl) * lc + sigm(vr) * rc;
            size_t orow = (size_t)blockIdx.x * 16 + p;
            g2c[orow * 128 + d] = cc;
            g2h[orow * 128 + d] = (_Float16)tanh_f(cc);
        }
    }
}

// ---------------------------------------------------------------------------
// k_hi: levels 3-10 + AND projection. One block per tree.
template <int NRT, bool GSRC>
__device__ __forceinline__ void level_pass(int np, int pass0, int opoff,
                                           const _Float16* hS, const _Float16* cS,
                                           const float* __restrict__ gc,
                                           const _Float16* __restrict__ gh, int rowbase,
                                           _Float16* hD, _Float16* cD,
                                           const _Float16* __restrict__ WpT,
                                           const int* s_op, int w, int lq, int lr) {
    f32x4 acc[NRT][4][2];
#pragma unroll
    for (int rt = 0; rt < NRT; ++rt)
#pragma unroll
        for (int g = 0; g < 4; ++g)
#pragma unroll
            for (int ti = 0; ti < 2; ++ti) acc[rt][g][ti] = (f32x4)0.f;

#pragma unroll
    for (int kk = 0; kk < 9; ++kk) {
        half8 bb[4][2];
#pragma unroll
        for (int g = 0; g < 4; ++g)
#pragma unroll
            for (int ti = 0; ti < 2; ++ti)
                bb[g][ti] = *(const half8*)(WpT + (g * 128 + w * 32 + ti * 16 + lr) * 288 + kk * 32 + lq * 8);
        half8 af[NRT];
        if (kk < 8) {
            int side = kk >> 2, ko = (kk & 3) * 32 + lq * 8;
#pragma unroll
            for (int rt = 0; rt < NRT; ++rt) {
                int pidx = pass0 + rt * 16 + lr; if (pidx > np - 1) pidx = np - 1;
                int child = 2 * pidx + side;
                if constexpr (GSRC)
                    af[rt] = *(const half8*)(gh + (size_t)(rowbase + child) * 128 + ko);
                else
                    af[rt] = *(const half8*)(hS + child * 128 + (ko ^ ((child & 15) << 3)));
            }
        } else {
#pragma unroll
            for (int rt = 0; rt < NRT; ++rt) {
                int pidx = pass0 + rt * 16 + lr; if (pidx > np - 1) pidx = np - 1;
                int op = s_op[opoff + pidx];
#pragma unroll
                for (int i = 0; i < 8; ++i)
                    af[rt][i] = (_Float16)((lq * 8 + i) == op ? 1.f : 0.f);
            }
        }
#pragma unroll
        for (int rt = 0; rt < NRT; ++rt)
#pragma unroll
            for (int g = 0; g < 4; ++g)
#pragma unroll
                for (int ti = 0; ti < 2; ++ti)
                    acc[rt][g][ti] = __builtin_amdgcn_mfma_f32_16x16x32_f16(af[rt], bb[g][ti], acc[rt][g][ti], 0, 0, 0);
    }

#pragma unroll
    for (int rt = 0; rt < NRT; ++rt)
#pragma unroll
        for (int j = 0; j < 4; ++j) {
            int p = pass0 + rt * 16 + lq * 4 + j;
            if (p < np) {
#pragma unroll
                for (int ti = 0; ti < 2; ++ti) {
                    int dcol = w * 32 + ti * 16 + lr;
                    float vi = acc[rt][0][ti][j], vl = acc[rt][1][ti][j];
                    float vr = acc[rt][2][ti][j], vu = acc[rt][3][ti][j];
                    float lc, rc;
                    if constexpr (GSRC) {
                        lc = gc[(size_t)(rowbase + 2 * p) * 128 + dcol];
                        rc = gc[(size_t)(rowbase + 2 * p + 1) * 128 + dcol];
                    } else {
                        lc = (float)cS[(2 * p) * 132 + dcol];
                        rc = (float)cS[(2 * p + 1) * 132 + dcol];
                    }
                    float cc = sigm(vi) * tanh_f(vu) + sigm(vl) * lc + sigm(vr) * rc;
                    cD[p * 132 + dcol] = (_Float16)cc;
                    hD[p * 128 + (dcol ^ ((p & 15) << 3))] = (_Float16)tanh_f(cc);
                }
            }
        }
}

__global__ __launch_bounds__(256, 1) void k_hi(const float* __restrict__ g2c,
                                               const _Float16* __restrict__ g2h,
                                               const int* __restrict__ op_idx,
                                               const _Float16* __restrict__ WpT,
                                               const float* __restrict__ Wa,
                                               const float* __restrict__ ba,
                                               float* __restrict__ c2,
                                               float* __restrict__ h2) {
    __shared__ int s_op[256];
    __shared__ _Float16 hA[128 * 128], cA[128 * 132];
    __shared__ _Float16 hB[64 * 128],  cB[64 * 132];
    const int t = threadIdx.x, w = t >> 6, l = t & 63, lr = l & 15, lq = l >> 4;
    const int tree = blockIdx.x;

    if (t < 255) s_op[t] = op_idx[tree * 2047 + 1792 + t];
    __syncthreads();

    // d=3 (np=128, global src, 2 passes)
    level_pass<4, true>(128, 0,  0, nullptr, nullptr, g2c, g2h, tree * 256, hA, cA, WpT, s_op, w, lq, lr);
    level_pass<4, true>(128, 64, 0, nullptr, nullptr, g2c, g2h, tree * 256, hA, cA, WpT, s_op, w, lq, lr);
    __syncthreads();
    level_pass<4, false>(64, 0, 128, hA, cA, nullptr, nullptr, 0, hB, cB, WpT, s_op, w, lq, lr);
    __syncthreads();
    level_pass<2, false>(32, 0, 192, hB, cB, nullptr, nullptr, 0, hA, cA, WpT, s_op, w, lq, lr);
    __syncthreads();
    level_pass<1, false>(16, 0, 224, hA, cA, nullptr, nullptr, 0, hB, cB, WpT, s_op, w, lq, lr);
    __syncthreads();
    level_pass<1, false>(8, 0, 240, hB, cB, nullptr, nullptr, 0, hA, cA, WpT, s_op, w, lq, lr);
    __syncthreads();
    level_pass<1, false>(4, 0, 248, hA, cA, nullptr, nullptr, 0, hB, cB, WpT, s_op, w, lq, lr);
    __syncthreads();
    level_pass<1, false>(2, 0, 252, hB, cB, nullptr, nullptr, 0, hA, cA, WpT, s_op, w, lq, lr);
    __syncthreads();
    level_pass<1, false>(1, 0, 254, hA, cA, nullptr, nullptr, 0, hB, cB, WpT, s_op, w, lq, lr);
    __syncthreads();

    // AND projection: root is row 0 of B buffers
    {
        int dd = t & 127;
        if (t < 128) {
            float a = ba[dd];
            for (int ll = 0; ll < 128; ++ll) a += (float)cB[ll] * Wa[ll * 128 + dd];
            c2[tree * 128 + dd] = a;
        } else {
            float a = ba[128 + dd];
            for (int ll = 0; ll < 128; ++ll) a += (float)hB[ll] * Wa[16384 + ll * 128 + dd];
            h2[tree * 128 + dd] = a;
        }
    }
}

// ---------------------------------------------------------------------------
__global__ __launch_bounds__(128) void k_final(const float* __restrict__ c2,
                                               const float* __restrict__ h2,
                                               const float* __restrict__ init_e,
                                               const float* __restrict__ Wo,
                                               const float* __restrict__ bo,
                                               float* __restrict__ out) {
    __shared__ float s[384];
    const int d = threadIdx.x;
    float cm = c2[d], hm = h2[d];
    for (int k = 1; k < 64; ++k) {
        cm = fminf(cm, c2[k * 128 + d]);
        hm = fminf(hm, h2[k * 128 + d]);
    }
    s[d] = init_e[d];
    s[128 + d] = cm;
    s[256 + d] = hm;
    __syncthreads();
    float a = bo[d];
    for (int l = 0; l < 384; ++l) a += s[l] * Wo[l * 128 + d];
    out[d] = tanhf(a);
}

// ---------------------------------------------------------------------------
extern "C" void kernel_launch(void* const* d_in, const int* in_sizes, int n_in,
                              void* d_out, int out_size, void* d_ws, size_t ws_size,
                              hipStream_t stream) {
    const float* node_emb = (const float*)d_in[0];
    const float* init_emb = (const float*)d_in[1];
    const float* char_emb = (const float*)d_in[2];
    const float* W_child  = (const float*)d_in[3];
    const float* b_child  = (const float*)d_in[4];
    const float* W_x      = (const float*)d_in[5];
    const float* b_x      = (const float*)d_in[6];
    const float* W_leaf   = (const float*)d_in[7];
    const float* b_leaf   = (const float*)d_in[8];
    const float* W_and    = (const float*)d_in[9];
    const float* b_and    = (const float*)d_in[10];
    const float* W_oend   = (const float*)d_in[11];
    const float* b_oend   = (const float*)d_in[12];
    const int* leaf_idx   = (const int*)d_in[13];
    const int* op_idx     = (const int*)d_in[14];
    float* out = (float*)d_out;
    (void)in_sizes; (void)n_in; (void)out_size; (void)ws_size;

    char* p = (char*)d_ws;
    auto carve = [&](size_t bytes) { char* r = p; p += (bytes + 255) & ~255ull; return r; };
    _Float16* WpT   = (_Float16*)carve((size_t)512 * 288 * 2);
    _Float16* WlT   = (_Float16*)carve((size_t)256 * 128 * 2);
    _Float16* c_tab = (_Float16*)carve((size_t)NNODES * 128 * 2);
    _Float16* h_tab = (_Float16*)carve((size_t)NNODES * 128 * 2);
    float*    g2c   = (float*)carve((size_t)16384 * 128 * 4);
    _Float16* g2h   = (_Float16*)carve((size_t)16384 * 128 * 2);
    float*    c2    = (float*)carve(64 * 128 * 4);
    float*    h2    = (float*)carve(64 * 128 * 4);

    k_prep_wpT  <<<512, 256, 0, stream>>>(W_child, WpT);
    k_prep_wlT  <<<128, 256, 0, stream>>>(W_leaf, WlT);
    k_prep_table<<<64, 256, 0, stream>>>(char_emb, W_x, b_x, b_child, WpT);
    k_prep_nodes<<<(NNODES + 31) / 32, 256, 0, stream>>>(node_emb, WlT, b_leaf, c_tab, h_tab);
    k_lo <<<1024, 256, 0, stream>>>(c_tab, h_tab, leaf_idx, op_idx, WpT, g2c, g2h);
    k_hi <<<64, 256, 0, stream>>>(g2c, g2h, op_idx, WpT, W_and, b_and, c2, h2);
    k_final<<<1, 128, 0, stream>>>(c2, h2, init_emb, W_oend, b_oend, out);
}

// Round 5
// 252.900 us; speedup vs baseline: 3.5504x; 1.0346x over previous
//
#include <hip/hip_runtime.h>

#define NNODES 50000

typedef _Float16 half8 __attribute__((ext_vector_type(8)));
typedef float f32x4 __attribute__((ext_vector_type(4)));

__device__ __forceinline__ float sigm(float x)   { return 1.f / (1.f + __expf(-x)); }
__device__ __forceinline__ float tanh_f(float x) { float e = __expf(2.f * x); return 1.f - 2.f / (e + 1.f); }

// ---------------------------------------------------------------------------
// WpT[512 cols][288 k] fp16. k<128: W_child[2g][k][d]; k<256: W_child[2g+1][k-128][d]
// (col c -> gate g=c>>7, d=c&127). k in 256..287 filled by k_prep_table (op tab).
__global__ __launch_bounds__(256) void k_prep_wpT(const float* __restrict__ Wc,
                                                  _Float16* __restrict__ WpT) {
    int i = blockIdx.x * 256 + threadIdx.x;      // 0..131071
    int c = i >> 8, k = i & 255;
    int g = c >> 7, d = c & 127;
    float v = (k < 128) ? Wc[(2 * g) * 16384 + k * 128 + d]
                        : Wc[(2 * g + 1) * 16384 + (k - 128) * 128 + d];
    WpT[c * 288 + k] = (_Float16)v;
}

// tab rows of WpT: WpT[c*288 + 256 + t] = char_emb[t]@W_x[gx] + b_x[gx] + b_child[2g] + b_child[2g+1]
__global__ __launch_bounds__(256) void k_prep_table(const float* __restrict__ ce,
                                                    const float* __restrict__ Wx,
                                                    const float* __restrict__ bx,
                                                    const float* __restrict__ bc,
                                                    _Float16* __restrict__ WpT) {
    int i = blockIdx.x * 256 + threadIdx.x;      // 0..16383
    int tt = i >> 9, c = i & 511;
    int g = c >> 7, d = c & 127;
    int gx = (g == 0) ? 0 : ((g == 3) ? 2 : 1);
    float acc = bx[gx * 128 + d] + bc[(2 * g) * 128 + d] + bc[(2 * g + 1) * 128 + d];
    const float* x = ce + tt * 128;
    const float* w = Wx + gx * 16384 + d;
    for (int l = 0; l < 128; ++l) acc += x[l] * w[l * 128];
    WpT[c * 288 + 256 + tt] = (_Float16)acc;
}

// WlT[256 cols][128 k] fp16
__global__ __launch_bounds__(256) void k_prep_wlT(const float* __restrict__ Wl,
                                                  _Float16* __restrict__ WlT) {
    int i = blockIdx.x * 256 + threadIdx.x;      // 0..32767
    int c = i >> 7, k = i & 127;
    WlT[i] = (_Float16)Wl[(c >> 7) * 16384 + k * 128 + (c & 127)];
}

// ---------------------------------------------------------------------------
// Leaf tables: [50000 x 128] fp32 -> c_tab fp16, h_tab fp16 via f16 MFMA
__global__ __launch_bounds__(256) void k_prep_nodes(const float* __restrict__ ne,
                                                    const _Float16* __restrict__ WlT,
                                                    const float* __restrict__ bl,
                                                    _Float16* __restrict__ c_tab,
                                                    _Float16* __restrict__ h_tab) {
    const int t = threadIdx.x;
    const int w = t >> 6, l = t & 63;
    const int lr = l & 15, lq = l >> 4;
    const int nb = blockIdx.x * 32;

    int arow[2];
#pragma unroll
    for (int rt = 0; rt < 2; ++rt) {
        int r = nb + rt * 16 + lr;
        arow[rt] = (r < NNODES) ? r : (NNODES - 1);
    }

    f32x4 acc[2][2][2];
#pragma unroll
    for (int rt = 0; rt < 2; ++rt)
#pragma unroll
        for (int g = 0; g < 2; ++g)
#pragma unroll
            for (int ti = 0; ti < 2; ++ti) acc[rt][g][ti] = (f32x4)0.f;

#pragma unroll
    for (int kk = 0; kk < 4; ++kk) {
        half8 af[2];
#pragma unroll
        for (int rt = 0; rt < 2; ++rt) {
            const float* src = ne + (size_t)arow[rt] * 128 + kk * 32 + lq * 8;
            float4 f0 = *(const float4*)src;
            float4 f1 = *(const float4*)(src + 4);
            half8 v;
            v[0] = (_Float16)f0.x; v[1] = (_Float16)f0.y; v[2] = (_Float16)f0.z; v[3] = (_Float16)f0.w;
            v[4] = (_Float16)f1.x; v[5] = (_Float16)f1.y; v[6] = (_Float16)f1.z; v[7] = (_Float16)f1.w;
            af[rt] = v;
        }
#pragma unroll
        for (int g = 0; g < 2; ++g)
#pragma unroll
            for (int ti = 0; ti < 2; ++ti) {
                int col = g * 128 + w * 32 + ti * 16 + lr;
                half8 bb = *(const half8*)(WlT + col * 128 + kk * 32 + lq * 8);
#pragma unroll
                for (int rt = 0; rt < 2; ++rt)
                    acc[rt][g][ti] = __builtin_amdgcn_mfma_f32_16x16x32_f16(af[rt], bb, acc[rt][g][ti], 0, 0, 0);
            }
    }

#pragma unroll
    for (int rt = 0; rt < 2; ++rt)
#pragma unroll
        for (int j = 0; j < 4; ++j) {
            int r = nb + rt * 16 + lq * 4 + j;
            if (r < NNODES) {
#pragma unroll
                for (int ti = 0; ti < 2; ++ti) {
                    int d = w * 32 + ti * 16 + lr;
                    float cc = acc[rt][0][ti][j] + bl[d];
                    float hp = acc[rt][1][ti][j] + bl[128 + d];
                    c_tab[(size_t)r * 128 + d] = (_Float16)cc;
                    h_tab[(size_t)r * 128 + d] = (_Float16)(sigm(hp) * tanh_f(cc));
                }
            }
        }
}

// ---------------------------------------------------------------------------
// k_lo: levels 0-2 fused. 1024 blocks x 512 threads (8 waves x 16-col slices).
// Block owns 64 L0-pairs -> 32 L1 -> 16 L2 outputs.
__global__ __launch_bounds__(512, 4) void k_lo(const _Float16* __restrict__ c_tab,
                                               const _Float16* __restrict__ h_tab,
                                               const int* __restrict__ leaf_idx,
                                               const int* __restrict__ op_idx,
                                               const _Float16* __restrict__ WpT,
                                               float* __restrict__ g2c,
                                               _Float16* __restrict__ g2h) {
    __shared__ int s_leaf[128];
    __shared__ int s_op[112];
    __shared__ _Float16 s_cst[128 * 132];   // child-c rows; later aliased as h1|c1
    __shared__ _Float16 s_h0[64 * 128];     // swizzled
    __shared__ _Float16 s_c0[64 * 132];
    _Float16* s_h1 = s_cst;                 // 32*128
    _Float16* s_c1 = s_cst + 32 * 128;      // 32*132

    const int t = threadIdx.x;
    const int w = t >> 6, l = t & 63, lr = l & 15, lq = l >> 4;
    const int ks = blockIdx.x >> 4, seg = blockIdx.x & 15;

    if (t < 128) s_leaf[t] = leaf_idx[ks * 2048 + seg * 128 + t];
    else if (t < 192) s_op[t - 128] = op_idx[ks * 2047 + seg * 64 + (t - 128)];
    else if (t < 224) s_op[64 + t - 192] = op_idx[ks * 2047 + 1024 + seg * 32 + (t - 192)];
    else if (t < 240) s_op[96 + t - 224] = op_idx[ks * 2047 + 1536 + seg * 16 + (t - 224)];
    __syncthreads();

    // stage child-c rows (consumed only after the post-GEMM barrier)
    {
        const int crow = t >> 2, coff = (t & 3) * 32;
        const _Float16* src = c_tab + (size_t)s_leaf[crow] * 128 + coff;
#pragma unroll
        for (int i = 0; i < 4; ++i)
            *(half8*)(s_cst + crow * 132 + coff + i * 8) = *(const half8*)(src + i * 8);
    }

    int grow[4][2], opv[4];
#pragma unroll
    for (int rt = 0; rt < 4; ++rt) {
        int pg = rt * 16 + lr;
        grow[rt][0] = s_leaf[2 * pg];
        grow[rt][1] = s_leaf[2 * pg + 1];
        opv[rt] = s_op[pg];
    }

    // ---- level 0 GEMM: 64 pairs, K=288 (one-hot op tail) ----
    f32x4 acc[4][4];
#pragma unroll
    for (int rt = 0; rt < 4; ++rt)
#pragma unroll
        for (int g = 0; g < 4; ++g) acc[rt][g] = (f32x4)0.f;

#pragma unroll
    for (int kk = 0; kk < 9; ++kk) {
        half8 a[4];
        if (kk < 8) {
            int side = kk >> 2, ko = (kk & 3) * 32 + lq * 8;
#pragma unroll
            for (int rt = 0; rt < 4; ++rt)
                a[rt] = *(const half8*)(h_tab + (size_t)grow[rt][side] * 128 + ko);
        } else {
#pragma unroll
            for (int rt = 0; rt < 4; ++rt)
#pragma unroll
                for (int i = 0; i < 8; ++i)
                    a[rt][i] = (_Float16)((lq * 8 + i) == opv[rt] ? 1.f : 0.f);
        }
#pragma unroll
        for (int g = 0; g < 4; ++g) {
            half8 bb = *(const half8*)(WpT + (g * 128 + w * 16 + lr) * 288 + kk * 32 + lq * 8);
#pragma unroll
            for (int rt = 0; rt < 4; ++rt)
                acc[rt][g] = __builtin_amdgcn_mfma_f32_16x16x32_f16(a[rt], bb, acc[rt][g], 0, 0, 0);
        }
    }
    __syncthreads();   // c-stage visible

    const int d = w * 16 + lr;
#pragma unroll
    for (int rt = 0; rt < 4; ++rt)
#pragma unroll
        for (int j = 0; j < 4; ++j) {
            int p = rt * 16 + lq * 4 + j;
            float vi = acc[rt][0][j], vl = acc[rt][1][j], vr = acc[rt][2][j], vu = acc[rt][3][j];
            float lc = (float)s_cst[(2 * p) * 132 + d];
            float rc = (float)s_cst[(2 * p + 1) * 132 + d];
            float cc = sigm(vi) * tanh_f(vu) + sigm(vl) * lc + sigm(vr) * rc;
            s_c0[p * 132 + d] = (_Float16)cc;
            s_h0[p * 128 + (d ^ ((p & 15) << 3))] = (_Float16)tanh_f(cc);
        }
    __syncthreads();   // h0/c0 ready; cst reads done -> alias safe

    // ---- level 1: 32 pairs ----
    int opv1[2];
    opv1[0] = s_op[64 + lr]; opv1[1] = s_op[64 + 16 + lr];
    f32x4 acc1[2][4];
#pragma unroll
    for (int rt = 0; rt < 2; ++rt)
#pragma unroll
        for (int g = 0; g < 4; ++g) acc1[rt][g] = (f32x4)0.f;

#pragma unroll
    for (int kk = 0; kk < 9; ++kk) {
        half8 a[2];
        if (kk < 8) {
            int side = kk >> 2, ko = (kk & 3) * 32 + lq * 8;
#pragma unroll
            for (int rt = 0; rt < 2; ++rt) {
                int child = 2 * (rt * 16 + lr) + side;
                a[rt] = *(const half8*)(s_h0 + child * 128 + (ko ^ ((child & 15) << 3)));
            }
        } else {
#pragma unroll
            for (int rt = 0; rt < 2; ++rt)
#pragma unroll
                for (int i = 0; i < 8; ++i)
                    a[rt][i] = (_Float16)((lq * 8 + i) == opv1[rt] ? 1.f : 0.f);
        }
#pragma unroll
        for (int g = 0; g < 4; ++g) {
            half8 bb = *(const half8*)(WpT + (g * 128 + w * 16 + lr) * 288 + kk * 32 + lq * 8);
#pragma unroll
            for (int rt = 0; rt < 2; ++rt)
                acc1[rt][g] = __builtin_amdgcn_mfma_f32_16x16x32_f16(a[rt], bb, acc1[rt][g], 0, 0, 0);
        }
    }

#pragma unroll
    for (int rt = 0; rt < 2; ++rt)
#pragma unroll
        for (int j = 0; j < 4; ++j) {
            int p = rt * 16 + lq * 4 + j;
            float vi = acc1[rt][0][j], vl = acc1[rt][1][j], vr = acc1[rt][2][j], vu = acc1[rt][3][j];
            float lc = (float)s_c0[(2 * p) * 132 + d];
            float rc = (float)s_c0[(2 * p + 1) * 132 + d];
            float cc = sigm(vi) * tanh_f(vu) + sigm(vl) * lc + sigm(vr) * rc;
            s_c1[p * 132 + d] = (_Float16)cc;
            s_h1[p * 128 + (d ^ ((p & 15) << 3))] = (_Float16)tanh_f(cc);
        }
    __syncthreads();

    // ---- level 2: 16 pairs -> global ----
    int opv2 = s_op[96 + lr];
    f32x4 acc2[4];
#pragma unroll
    for (int g = 0; g < 4; ++g) acc2[g] = (f32x4)0.f;

#pragma unroll
    for (int kk = 0; kk < 9; ++kk) {
        half8 a;
        if (kk < 8) {
            int side = kk >> 2, ko = (kk & 3) * 32 + lq * 8;
            int child = 2 * lr + side;
            a = *(const half8*)(s_h1 + child * 128 + (ko ^ ((child & 15) << 3)));
        } else {
#pragma unroll
            for (int i = 0; i < 8; ++i)
                a[i] = (_Float16)((lq * 8 + i) == opv2 ? 1.f : 0.f);
        }
#pragma unroll
        for (int g = 0; g < 4; ++g) {
            half8 bb = *(const half8*)(WpT + (g * 128 + w * 16 + lr) * 288 + kk * 32 + lq * 8);
            acc2[g] = __builtin_amdgcn_mfma_f32_16x16x32_f16(a, bb, acc2[g], 0, 0, 0);
        }
    }

#pragma unroll
    for (int j = 0; j < 4; ++j) {
        int p = lq * 4 + j;
        float vi = acc2[0][j], vl = acc2[1][j], vr = acc2[2][j], vu = acc2[3][j];
        float lc = (float)s_c1[(2 * p) * 132 + d];
        float rc = (float)s_c1[(2 * p + 1) * 132 + d];
        float cc = sigm(vi) * tanh_f(vu) + sigm(vl) * lc + sigm(vr) * rc;
        size_t orow = (size_t)blockIdx.x * 16 + p;
        g2c[orow * 128 + d] = cc;
        g2h[orow * 128 + d] = (_Float16)tanh_f(cc);
    }
}

// ---------------------------------------------------------------------------
// Generic mid level: 32 pairs/block, 512 threads, no LDS. Children are
// contiguous rows 2p,2p+1 of the previous level's dense output.
__global__ __launch_bounds__(512, 4) void k_level(const float* __restrict__ c_src,
                                                  const _Float16* __restrict__ h_src,
                                                  float* __restrict__ c_dst,
                                                  _Float16* __restrict__ h_dst,
                                                  const _Float16* __restrict__ WpT,
                                                  const int* __restrict__ op_idx,
                                                  int op_start, int mshift) {
    const int t = threadIdx.x;
    const int w = t >> 6, l = t & 63, lr = l & 15, lq = l >> 4;
    const int pbase = blockIdx.x * 32;

    int opv[2];
#pragma unroll
    for (int rt = 0; rt < 2; ++rt) {
        int pg = pbase + rt * 16 + lr;
        int ksx = pg >> mshift, j = pg & ((1 << mshift) - 1);
        opv[rt] = op_idx[ksx * 2047 + op_start + j];
    }

    f32x4 acc[2][4];
#pragma unroll
    for (int rt = 0; rt < 2; ++rt)
#pragma unroll
        for (int g = 0; g < 4; ++g) acc[rt][g] = (f32x4)0.f;

#pragma unroll
    for (int kk = 0; kk < 9; ++kk) {
        half8 a[2];
        if (kk < 8) {
            int side = kk >> 2, ko = (kk & 3) * 32 + lq * 8;
#pragma unroll
            for (int rt = 0; rt < 2; ++rt) {
                int row = 2 * (pbase + rt * 16 + lr) + side;
                a[rt] = *(const half8*)(h_src + (size_t)row * 128 + ko);
            }
        } else {
#pragma unroll
            for (int rt = 0; rt < 2; ++rt)
#pragma unroll
                for (int i = 0; i < 8; ++i)
                    a[rt][i] = (_Float16)((lq * 8 + i) == opv[rt] ? 1.f : 0.f);
        }
#pragma unroll
        for (int g = 0; g < 4; ++g) {
            half8 bb = *(const half8*)(WpT + (g * 128 + w * 16 + lr) * 288 + kk * 32 + lq * 8);
#pragma unroll
            for (int rt = 0; rt < 2; ++rt)
                acc[rt][g] = __builtin_amdgcn_mfma_f32_16x16x32_f16(a[rt], bb, acc[rt][g], 0, 0, 0);
        }
    }

    const int d = w * 16 + lr;
#pragma unroll
    for (int rt = 0; rt < 2; ++rt)
#pragma unroll
        for (int j = 0; j < 4; ++j) {
            int p = pbase + rt * 16 + lq * 4 + j;
            float vi = acc[rt][0][j], vl = acc[rt][1][j], vr = acc[rt][2][j], vu = acc[rt][3][j];
            float lc = c_src[(size_t)(2 * p) * 128 + d];
            float rc = c_src[(size_t)(2 * p + 1) * 128 + d];
            float cc = sigm(vi) * tanh_f(vu) + sigm(vl) * lc + sigm(vr) * rc;
            c_dst[(size_t)p * 128 + d] = cc;
            h_dst[(size_t)p * 128 + d] = (_Float16)tanh_f(cc);
        }
}

// ---------------------------------------------------------------------------
// k_deep: levels 6-10 + AND projection. One block per tree, WpT held in regs.
template <bool GSRC>
__device__ __forceinline__ void deep_pass(int np, int opoff,
                                          const _Float16* hS, const _Float16* cS,
                                          const _Float16* __restrict__ gh,
                                          const float* __restrict__ gc, int rowbase,
                                          _Float16* hD, _Float16* cD,
                                          const half8 (&B)[9][4],
                                          const int* s_op, int w, int lq, int lr) {
    f32x4 acc[4];
#pragma unroll
    for (int g = 0; g < 4; ++g) acc[g] = (f32x4)0.f;
    int pidx = lr < np ? lr : np - 1;
    int op = s_op[opoff + pidx];
#pragma unroll
    for (int kk = 0; kk < 9; ++kk) {
        half8 a;
        if (kk < 8) {
            int side = kk >> 2, ko = (kk & 3) * 32 + lq * 8;
            int child = 2 * pidx + side;
            if constexpr (GSRC)
                a = *(const half8*)(gh + (size_t)(rowbase + child) * 128 + ko);
            else
                a = *(const half8*)(hS + child * 128 + (ko ^ ((child & 15) << 3)));
        } else {
#pragma unroll
            for (int i = 0; i < 8; ++i)
                a[i] = (_Float16)((lq * 8 + i) == op ? 1.f : 0.f);
        }
#pragma unroll
        for (int g = 0; g < 4; ++g)
            acc[g] = __builtin_amdgcn_mfma_f32_16x16x32_f16(a, B[kk][g], acc[g], 0, 0, 0);
    }
    const int d = w * 16 + lr;
#pragma unroll
    for (int j = 0; j < 4; ++j) {
        int p = lq * 4 + j;
        if (p < np) {
            float vi = acc[0][j], vl = acc[1][j], vr = acc[2][j], vu = acc[3][j];
            float lc, rc;
            if constexpr (GSRC) {
                lc = gc[(size_t)(rowbase + 2 * p) * 128 + d];
                rc = gc[(size_t)(rowbase + 2 * p + 1) * 128 + d];
            } else {
                lc = (float)cS[(2 * p) * 132 + d];
                rc = (float)cS[(2 * p + 1) * 132 + d];
            }
            float cc = sigm(vi) * tanh_f(vu) + sigm(vl) * lc + sigm(vr) * rc;
            cD[p * 132 + d] = (_Float16)cc;
            hD[p * 128 + (d ^ ((p & 15) << 3))] = (_Float16)tanh_f(cc);
        }
    }
}

__global__ __launch_bounds__(512, 2) void k_deep(const float* __restrict__ g5c,
                                                 const _Float16* __restrict__ g5h,
                                                 const int* __restrict__ op_idx,
                                                 const _Float16* __restrict__ WpT,
                                                 const float* __restrict__ Wa,
                                                 const float* __restrict__ ba,
                                                 float* __restrict__ c2,
                                                 float* __restrict__ h2) {
    __shared__ int s_op[32];
    __shared__ _Float16 hA[16 * 128], cA[16 * 132];
    __shared__ _Float16 hB[8 * 128],  cB[8 * 132];
    const int t = threadIdx.x, w = t >> 6, l = t & 63, lr = l & 15, lq = l >> 4;
    const int tree = blockIdx.x;

    if (t < 31) s_op[t] = op_idx[tree * 2047 + 2016 + t];   // L6:0..15 L7:16..23 L8:24..27 L9:28..29 L10:30
    __syncthreads();

    half8 B[9][4];
#pragma unroll
    for (int kk = 0; kk < 9; ++kk)
#pragma unroll
        for (int g = 0; g < 4; ++g)
            B[kk][g] = *(const half8*)(WpT + (g * 128 + w * 16 + lr) * 288 + kk * 32 + lq * 8);

    deep_pass<true >(16,  0, nullptr, nullptr, g5h, g5c, tree * 32, hA, cA, B, s_op, w, lq, lr);
    __syncthreads();
    deep_pass<false>( 8, 16, hA, cA, nullptr, nullptr, 0, hB, cB, B, s_op, w, lq, lr);
    __syncthreads();
    deep_pass<false>( 4, 24, hB, cB, nullptr, nullptr, 0, hA, cA, B, s_op, w, lq, lr);
    __syncthreads();
    deep_pass<false>( 2, 28, hA, cA, nullptr, nullptr, 0, hB, cB, B, s_op, w, lq, lr);
    __syncthreads();
    deep_pass<false>( 1, 30, hB, cB, nullptr, nullptr, 0, hA, cA, B, s_op, w, lq, lr);
    __syncthreads();

    // AND projection (root = row 0 of A; p=0 swizzle is identity)
    if (t < 256) {
        int dd = t & 127;
        if (t < 128) {
            float a = ba[dd];
            for (int ll = 0; ll < 128; ++ll) a += (float)cA[ll] * Wa[ll * 128 + dd];
            c2[tree * 128 + dd] = a;
        } else {
            float a = ba[128 + dd];
            for (int ll = 0; ll < 128; ++ll) a += (float)hA[ll] * Wa[16384 + ll * 128 + dd];
            h2[tree * 128 + dd] = a;
        }
    }
}

// ---------------------------------------------------------------------------
__global__ __launch_bounds__(128) void k_final(const float* __restrict__ c2,
                                               const float* __restrict__ h2,
                                               const float* __restrict__ init_e,
                                               const float* __restrict__ Wo,
                                               const float* __restrict__ bo,
                                               float* __restrict__ out) {
    __shared__ float s[384];
    const int d = threadIdx.x;
    float cm = c2[d], hm = h2[d];
    for (int k = 1; k < 64; ++k) {
        cm = fminf(cm, c2[k * 128 + d]);
        hm = fminf(hm, h2[k * 128 + d]);
    }
    s[d] = init_e[d];
    s[128 + d] = cm;
    s[256 + d] = hm;
    __syncthreads();
    float a = bo[d];
    for (int l = 0; l < 384; ++l) a += s[l] * Wo[l * 128 + d];
    out[d] = tanhf(a);
}

// ---------------------------------------------------------------------------
extern "C" void kernel_launch(void* const* d_in, const int* in_sizes, int n_in,
                              void* d_out, int out_size, void* d_ws, size_t ws_size,
                              hipStream_t stream) {
    const float* node_emb = (const float*)d_in[0];
    const float* init_emb = (const float*)d_in[1];
    const float* char_emb = (const float*)d_in[2];
    const float* W_child  = (const float*)d_in[3];
    const float* b_child  = (const float*)d_in[4];
    const float* W_x      = (const float*)d_in[5];
    const float* b_x      = (const float*)d_in[6];
    const float* W_leaf   = (const float*)d_in[7];
    const float* b_leaf   = (const float*)d_in[8];
    const float* W_and    = (const float*)d_in[9];
    const float* b_and    = (const float*)d_in[10];
    const float* W_oend   = (const float*)d_in[11];
    const float* b_oend   = (const float*)d_in[12];
    const int* leaf_idx   = (const int*)d_in[13];
    const int* op_idx     = (const int*)d_in[14];
    float* out = (float*)d_out;
    (void)in_sizes; (void)n_in; (void)out_size; (void)ws_size;

    char* p = (char*)d_ws;
    auto carve = [&](size_t bytes) { char* r = p; p += (bytes + 255) & ~255ull; return r; };
    _Float16* WpT   = (_Float16*)carve((size_t)512 * 288 * 2);
    _Float16* WlT   = (_Float16*)carve((size_t)256 * 128 * 2);
    _Float16* c_tab = (_Float16*)carve((size_t)NNODES * 128 * 2);
    _Float16* h_tab = (_Float16*)carve((size_t)NNODES * 128 * 2);
    float*    g2c   = (float*)carve((size_t)16384 * 128 * 4);
    _Float16* g2h   = (_Float16*)carve((size_t)16384 * 128 * 2);
    float*    g3c   = (float*)carve((size_t)8192 * 128 * 4);
    _Float16* g3h   = (_Float16*)carve((size_t)8192 * 128 * 2);
    float*    g4c   = (float*)carve((size_t)4096 * 128 * 4);
    _Float16* g4h   = (_Float16*)carve((size_t)4096 * 128 * 2);
    float*    g5c   = (float*)carve((size_t)2048 * 128 * 4);
    _Float16* g5h   = (_Float16*)carve((size_t)2048 * 128 * 2);
    float*    c2    = (float*)carve(64 * 128 * 4);
    float*    h2    = (float*)carve(64 * 128 * 4);

    k_prep_wpT  <<<512, 256, 0, stream>>>(W_child, WpT);
    k_prep_wlT  <<<128, 256, 0, stream>>>(W_leaf, WlT);
    k_prep_table<<<64, 256, 0, stream>>>(char_emb, W_x, b_x, b_child, WpT);
    k_prep_nodes<<<(NNODES + 31) / 32, 256, 0, stream>>>(node_emb, WlT, b_leaf, c_tab, h_tab);

    k_lo   <<<1024, 512, 0, stream>>>(c_tab, h_tab, leaf_idx, op_idx, WpT, g2c, g2h);
    k_level<<<256, 512, 0, stream>>>(g2c, g2h, g3c, g3h, WpT, op_idx, 1792, 7);  // L3
    k_level<<<128, 512, 0, stream>>>(g3c, g3h, g4c, g4h, WpT, op_idx, 1920, 6);  // L4
    k_level<<< 64, 512, 0, stream>>>(g4c, g4h, g5c, g5h, WpT, op_idx, 1984, 5);  // L5
    k_deep <<< 64, 512, 0, stream>>>(g5c, g5h, op_idx, WpT, W_and, b_and, c2, h2);
    k_final<<<1, 128, 0, stream>>>(c2, h2, init_emb, W_oend, b_oend, out);
}